// Round 1
// baseline (494.431 us; speedup 1.0000x reference)
//
#include <hip/hip_runtime.h>

// Problem constants
#define B_   512
#define D_IN 64
#define D_TRF 5120
#define P_   32
#define E_   160
#define D_OUT 3000
#define PAD_ 61
#define D_CL 4998          // D_TRF - 2*PAD
#define INV_SCALE 0.07905694150420949f   // 1/sqrt(160)
#define N_PAD 3008         // D_OUT padded to 64-multiple (47*64)

typedef __attribute__((ext_vector_type(4))) float floatx4;
typedef __attribute__((ext_vector_type(8))) short short8;

static __device__ __forceinline__ unsigned short f2bf(float f) {
    unsigned int u = __float_as_uint(f);
    unsigned int r = (u + 0x7fffu + ((u >> 16) & 1u)) >> 16;
    return (unsigned short)r;
}

// ---------------------------------------------------------------------------
// K0: cast lin_w [3000,5120] f32 -> [3008,5120] bf16 (pad rows zeroed)
// ---------------------------------------------------------------------------
__global__ __launch_bounds__(256) void k_castw(const float* __restrict__ w,
                                               unsigned short* __restrict__ wb) {
    size_t i4 = ((size_t)blockIdx.x * 256 + threadIdx.x) * 4;   // 4 elems/thread
    size_t o = i4 / D_TRF;   // 5120 % 4 == 0 -> all 4 elems same row
    ushort4 s;
    if (o < D_OUT) {
        float4 v = *(const float4*)(w + i4);
        s.x = f2bf(v.x); s.y = f2bf(v.y); s.z = f2bf(v.z); s.w = f2bf(v.w);
    } else {
        s.x = s.y = s.z = s.w = 0;
    }
    *(ushort4*)(wb + i4) = s;
}

// ---------------------------------------------------------------------------
// K1: cl = (x*std+mean) @ mat, with 61-zero pad both sides -> [512,5120]
// grid (64 b-groups of 8, 4 j-chunks of 1250)
// ---------------------------------------------------------------------------
__global__ __launch_bounds__(256) void k_cl(const float* __restrict__ x,
                                            const float* __restrict__ stdv,
                                            const float* __restrict__ meanv,
                                            const float* __restrict__ mat,
                                            float* __restrict__ cl) {
    int bg = blockIdx.x, jc = blockIdx.y, tid = threadIdx.x;
    __shared__ float t[8 * 64];
    for (int idx = tid; idx < 8 * 64; idx += 256) {
        int i = idx >> 6, k = idx & 63;
        t[idx] = x[(size_t)(bg * 8 + i) * 64 + k] * stdv[k] + meanv[k];
    }
    __syncthreads();

    // zero pads
    if (jc == 0) {
        for (int idx = tid; idx < 8 * PAD_; idx += 256) {
            int i = idx / PAD_, jj = idx - i * PAD_;
            cl[(size_t)(bg * 8 + i) * D_TRF + jj] = 0.f;
        }
    } else if (jc == 3) {
        for (int idx = tid; idx < 8 * PAD_; idx += 256) {
            int i = idx / PAD_, jj = idx - i * PAD_;
            cl[(size_t)(bg * 8 + i) * D_TRF + (D_TRF - PAD_) + jj] = 0.f;
        }
    }

    int j0 = jc * 1250;
    int jend = min(D_CL, j0 + 1250);
    for (int j = j0 + tid; j < jend; j += 256) {
        float acc[8] = {};
        #pragma unroll 16
        for (int k = 0; k < 64; ++k) {
            float m = mat[(size_t)k * D_CL + j];
            #pragma unroll
            for (int i = 0; i < 8; ++i) acc[i] += t[i * 64 + k] * m;
        }
        #pragma unroll
        for (int i = 0; i < 8; ++i)
            cl[(size_t)(bg * 8 + i) * D_TRF + PAD_ + j] = acc[i];
    }
}

// ---------------------------------------------------------------------------
// K2: per-row LayerNorm + Q/K/V projections (fp32). grid = 512 (one b each)
// Q[b,p,f] = sum_e xn[p,e]*wq[f,e] + bq[f]
// ---------------------------------------------------------------------------
__global__ __launch_bounds__(256) void k_qkv(const float* __restrict__ cl,
                                             const float* __restrict__ ln_g,
                                             const float* __restrict__ ln_b,
                                             const float* __restrict__ wq, const float* __restrict__ bq,
                                             const float* __restrict__ wk, const float* __restrict__ bk,
                                             const float* __restrict__ wv, const float* __restrict__ bv,
                                             float* __restrict__ Q, float* __restrict__ K,
                                             float* __restrict__ V) {
    int b = blockIdx.x, tid = threadIdx.x;
    __shared__ float xn[D_TRF];
    __shared__ float wqs[E_ * 17], wks[E_ * 17], wvs[E_ * 17];  // 16-col chunks, pad 17
    __shared__ float redA[4], redB[4];
    __shared__ float sMu, sRstd;

    const float* row = cl + (size_t)b * D_TRF;
    float s = 0.f, s2 = 0.f;
    for (int i = tid; i < D_TRF; i += 256) {
        float v = row[i];
        xn[i] = v;
        s += v; s2 += v * v;
    }
    #pragma unroll
    for (int off = 32; off; off >>= 1) {
        s  += __shfl_down(s, off);
        s2 += __shfl_down(s2, off);
    }
    if ((tid & 63) == 0) { redA[tid >> 6] = s; redB[tid >> 6] = s2; }
    __syncthreads();
    if (tid == 0) {
        float S = redA[0] + redA[1] + redA[2] + redA[3];
        float S2 = redB[0] + redB[1] + redB[2] + redB[3];
        float mu = S / (float)D_TRF;
        float var = S2 / (float)D_TRF - mu * mu;
        sMu = mu; sRstd = rsqrtf(var + 1e-5f);
    }
    __syncthreads();
    float mu = sMu, rs = sRstd;
    for (int i = tid; i < D_TRF; i += 256)
        xn[i] = (xn[i] - mu) * rs * ln_g[i] + ln_b[i];

    // thread owns p = pgrp+8r (r<4), f = flane+32m (m<5)
    int pgrp = tid >> 5, flane = tid & 31;
    float aq[5][4] = {}, ak[5][4] = {}, av[5][4] = {};

    for (int c = 0; c < 10; ++c) {
        int e0 = c * 16;
        __syncthreads();
        for (int idx = tid; idx < E_ * 16; idx += 256) {
            int f = idx >> 4, el = idx & 15;
            wqs[f * 17 + el] = wq[(size_t)f * E_ + e0 + el];
            wks[f * 17 + el] = wk[(size_t)f * E_ + e0 + el];
            wvs[f * 17 + el] = wv[(size_t)f * E_ + e0 + el];
        }
        __syncthreads();
        #pragma unroll
        for (int el = 0; el < 16; ++el) {
            float xv[4];
            #pragma unroll
            for (int r = 0; r < 4; ++r)
                xv[r] = xn[(pgrp + 8 * r) * E_ + e0 + el];
            #pragma unroll
            for (int m = 0; m < 5; ++m) {
                int f = flane + 32 * m;
                float q_ = wqs[f * 17 + el];
                float k_ = wks[f * 17 + el];
                float v_ = wvs[f * 17 + el];
                #pragma unroll
                for (int r = 0; r < 4; ++r) {
                    aq[m][r] += xv[r] * q_;
                    ak[m][r] += xv[r] * k_;
                    av[m][r] += xv[r] * v_;
                }
            }
        }
    }
    #pragma unroll
    for (int m = 0; m < 5; ++m) {
        int f = flane + 32 * m;
        float bq_ = bq[f], bk_ = bk[f], bv_ = bv[f];
        #pragma unroll
        for (int r = 0; r < 4; ++r) {
            int p = pgrp + 8 * r;
            size_t o = ((size_t)b * P_ + p) * E_ + f;
            Q[o] = aq[m][r] + bq_;
            K[o] = ak[m][r] + bk_;
            V[o] = av[m][r] + bv_;
        }
    }
}

// ---------------------------------------------------------------------------
// K3: attention per b: dot=Q K^T/sqrt(E); softmax over dim p; h = att@V + cl
// ---------------------------------------------------------------------------
__global__ __launch_bounds__(256) void k_attn(const float* __restrict__ Q,
                                              const float* __restrict__ K,
                                              const float* __restrict__ V,
                                              const float* __restrict__ cl,
                                              float* __restrict__ h) {
    int b = blockIdx.x, tid = threadIdx.x;
    __shared__ float Qs[P_ * E_];
    __shared__ float KsT[E_ * 33];   // transposed, padded
    __shared__ float att[P_ * P_];

    const float* Qg = Q + (size_t)b * D_TRF;
    const float* Kg = K + (size_t)b * D_TRF;
    for (int idx = tid; idx < D_TRF; idx += 256) {
        Qs[idx] = Qg[idx];
        int q = idx / E_, e = idx - q * E_;
        KsT[e * 33 + q] = Kg[idx];
    }
    __syncthreads();

    for (int idx = tid; idx < P_ * P_; idx += 256) {
        int p = idx >> 5, q = idx & 31;
        const float* qrow = Qs + p * E_;
        float a = 0.f;
        #pragma unroll 8
        for (int e = 0; e < E_; ++e) a += qrow[e] * KsT[e * 33 + q];
        att[idx] = a * INV_SCALE;
    }
    __syncthreads();

    if (tid < 32) {
        int q = tid;
        float mx = -1e30f;
        #pragma unroll
        for (int p = 0; p < P_; ++p) mx = fmaxf(mx, att[p * 32 + q]);
        float sum = 0.f;
        #pragma unroll
        for (int p = 0; p < P_; ++p) {
            float e_ = expf(att[p * 32 + q] - mx);
            att[p * 32 + q] = e_;
            sum += e_;
        }
        float inv = 1.f / sum;
        #pragma unroll
        for (int p = 0; p < P_; ++p) att[p * 32 + q] *= inv;
    }
    __syncthreads();

    const float* Vg = V + (size_t)b * D_TRF;
    const float* clr = cl + (size_t)b * D_TRF;
    for (int idx = tid; idx < D_TRF; idx += 256) {
        int p = idx / E_, e = idx - p * E_;
        const float* ar = att + p * 32;
        float a = 0.f;
        #pragma unroll
        for (int q = 0; q < P_; ++q) a += ar[q] * Vg[q * E_ + e];
        h[(size_t)b * D_TRF + idx] = a + clr[idx];
    }
}

// ---------------------------------------------------------------------------
// K4: Better_Transformer: o = (h*g+b) @ bt_w + bt_b; y = Supact(o) + h
// writes y as bf16 for the MFMA head. grid = 512
// ---------------------------------------------------------------------------
__global__ __launch_bounds__(256) void k_bt(const float* __restrict__ h,
                                            const float* __restrict__ bt_w,
                                            const float* __restrict__ bt_b,
                                            const float* __restrict__ bt_gain,
                                            const float* __restrict__ bt_bias,
                                            const float* __restrict__ sup_gamma,
                                            const float* __restrict__ sup_beta,
                                            unsigned short* __restrict__ yb) {
    int b = blockIdx.x, tid = threadIdx.x;
    __shared__ float x2s[D_TRF];
    __shared__ float wchunk[16 * E_];
    float gg = bt_gain[0], bbias = bt_bias[0];
    const float* hr = h + (size_t)b * D_TRF;
    for (int i = tid; i < D_TRF; i += 256) x2s[i] = hr[i] * gg + bbias;

    int pgrp = tid >> 5, flane = tid & 31;
    float acc[5][4] = {};

    for (int c = 0; c < 10; ++c) {
        int e0 = c * 16;
        __syncthreads();
        for (int idx = tid; idx < 16 * E_; idx += 256)
            wchunk[idx] = bt_w[(size_t)e0 * E_ + idx];   // [el][f], f contiguous
        __syncthreads();
        #pragma unroll
        for (int el = 0; el < 16; ++el) {
            float xv[4];
            #pragma unroll
            for (int r = 0; r < 4; ++r)
                xv[r] = x2s[(pgrp + 8 * r) * E_ + e0 + el];
            #pragma unroll
            for (int m = 0; m < 5; ++m) {
                float w_ = wchunk[el * E_ + flane + 32 * m];
                #pragma unroll
                for (int r = 0; r < 4; ++r) acc[m][r] += xv[r] * w_;
            }
        }
    }
    #pragma unroll
    for (int m = 0; m < 5; ++m) {
        int f = flane + 32 * m;
        float bb = bt_b[f];
        #pragma unroll
        for (int r = 0; r < 4; ++r) {
            int p = pgrp + 8 * r;
            int i = p * E_ + f;
            float o = acc[m][r] + bb;
            float sig = 1.f / (1.f + expf(-sup_beta[i] * o));
            float y = (sup_gamma[i] + sig * (1.f - sup_gamma[i])) * o + hr[i];
            yb[(size_t)b * D_TRF + i] = f2bf(y);
        }
    }
}

// ---------------------------------------------------------------------------
// K5: out = (y @ lin_w^T + lin_b) * out_gain + out_bias, bf16 MFMA 16x16x32
// Block tile 64(b) x 64(o): 4 waves (2x2), each wave 32x32 via 2x2 frags.
// A = y_bf16 [512,5120]; B = w_bf16 [3008,5120] (both [rows][K], row-major).
// ---------------------------------------------------------------------------
__global__ __launch_bounds__(256) void k_lin(const unsigned short* __restrict__ yb,
                                             const unsigned short* __restrict__ wb,
                                             const float* __restrict__ lin_b,
                                             const float* __restrict__ out_gain,
                                             const float* __restrict__ out_bias,
                                             float* __restrict__ out) {
    int ot = blockIdx.x, bt = blockIdx.y;
    int tid = threadIdx.x;
    int wid = tid >> 6, lane = tid & 63;
    int wm = wid >> 1, wn = wid & 1;
    int l16 = lane & 15, quad = lane >> 4;

    int b_base = bt * 64 + wm * 32;
    int o_base = ot * 64 + wn * 32;

    size_t aoff0 = (size_t)(b_base + l16) * D_TRF + quad * 8;
    size_t aoff1 = aoff0 + (size_t)16 * D_TRF;
    size_t boff0 = (size_t)(o_base + l16) * D_TRF + quad * 8;
    size_t boff1 = boff0 + (size_t)16 * D_TRF;

    floatx4 acc00 = {0.f, 0.f, 0.f, 0.f};
    floatx4 acc01 = {0.f, 0.f, 0.f, 0.f};
    floatx4 acc10 = {0.f, 0.f, 0.f, 0.f};
    floatx4 acc11 = {0.f, 0.f, 0.f, 0.f};

    for (int k0 = 0; k0 < D_TRF; k0 += 32) {
        short8 a0 = *(const short8*)(yb + aoff0 + k0);
        short8 a1 = *(const short8*)(yb + aoff1 + k0);
        short8 b0 = *(const short8*)(wb + boff0 + k0);
        short8 b1 = *(const short8*)(wb + boff1 + k0);
        acc00 = __builtin_amdgcn_mfma_f32_16x16x32_bf16(a0, b0, acc00, 0, 0, 0);
        acc01 = __builtin_amdgcn_mfma_f32_16x16x32_bf16(a0, b1, acc01, 0, 0, 0);
        acc10 = __builtin_amdgcn_mfma_f32_16x16x32_bf16(a1, b0, acc10, 0, 0, 0);
        acc11 = __builtin_amdgcn_mfma_f32_16x16x32_bf16(a1, b1, acc11, 0, 0, 0);
    }

    float g = out_gain[0], ob = out_bias[0];
    floatx4 accs[2][2] = {{acc00, acc01}, {acc10, acc11}};
    #pragma unroll
    for (int i = 0; i < 2; ++i) {
        int brow = b_base + i * 16 + quad * 4;   // row = quad*4 + reg
        #pragma unroll
        for (int j = 0; j < 2; ++j) {
            int ocol = o_base + j * 16 + l16;    // col = lane&15
            if (ocol >= D_OUT) continue;
            float cadd = lin_b[ocol] * g + ob;
            #pragma unroll
            for (int r = 0; r < 4; ++r)
                out[(size_t)(brow + r) * D_OUT + ocol] = accs[i][j][r] * g + cadd;
        }
    }
}

// ---------------------------------------------------------------------------
// Workspace layout (bytes)
// ---------------------------------------------------------------------------
#define SZ_ROWF ((size_t)B_ * D_TRF * 4)            // 10,485,760
#define OFF_CL  ((size_t)0)
#define OFF_H   (OFF_CL + SZ_ROWF)
#define OFF_Q   (OFF_H + SZ_ROWF)
#define OFF_K   (OFF_Q + SZ_ROWF)
#define OFF_V   (OFF_K + SZ_ROWF)
#define OFF_WB  (OFF_V + SZ_ROWF)                   // 3008*5120*2 = 30,801,920
#define OFF_YB  OFF_Q                               // reuse Q after attention

extern "C" void kernel_launch(void* const* d_in, const int* in_sizes, int n_in,
                              void* d_out, int out_size, void* d_ws, size_t ws_size,
                              hipStream_t stream) {
    const float* x        = (const float*)d_in[0];
    const float* stdv     = (const float*)d_in[1];
    const float* meanv    = (const float*)d_in[2];
    const float* mat      = (const float*)d_in[3];
    const float* ln_g     = (const float*)d_in[4];
    const float* ln_b     = (const float*)d_in[5];
    const float* wq       = (const float*)d_in[6];
    const float* bq       = (const float*)d_in[7];
    const float* wk       = (const float*)d_in[8];
    const float* bk       = (const float*)d_in[9];
    const float* wv       = (const float*)d_in[10];
    const float* bv       = (const float*)d_in[11];
    const float* bt_w     = (const float*)d_in[12];
    const float* bt_b     = (const float*)d_in[13];
    const float* bt_gain  = (const float*)d_in[14];
    const float* bt_bias  = (const float*)d_in[15];
    const float* sup_g    = (const float*)d_in[16];
    const float* sup_b    = (const float*)d_in[17];
    const float* lin_w    = (const float*)d_in[18];
    const float* lin_b    = (const float*)d_in[19];
    const float* out_gain = (const float*)d_in[20];
    const float* out_bias = (const float*)d_in[21];

    char* ws = (char*)d_ws;
    float* cl = (float*)(ws + OFF_CL);
    float* h  = (float*)(ws + OFF_H);
    float* Q  = (float*)(ws + OFF_Q);
    float* K  = (float*)(ws + OFF_K);
    float* V  = (float*)(ws + OFF_V);
    unsigned short* yb = (unsigned short*)(ws + OFF_YB);
    unsigned short* wb = (unsigned short*)(ws + OFF_WB);
    float* out = (float*)d_out;

    // 3008*5120/4 elems-per-thread/256 threads = 15040 blocks
    k_castw<<<15040, 256, 0, stream>>>(lin_w, wb);
    k_cl<<<dim3(64, 4), 256, 0, stream>>>(x, stdv, meanv, mat, cl);
    k_qkv<<<512, 256, 0, stream>>>(cl, ln_g, ln_b, wq, bq, wk, bk, wv, bv, Q, K, V);
    k_attn<<<512, 256, 0, stream>>>(Q, K, V, cl, h);
    k_bt<<<512, 256, 0, stream>>>(h, bt_w, bt_b, bt_gain, bt_bias, sup_g, sup_b, yb);
    k_lin<<<dim3(47, 8), 256, 0, stream>>>(yb, wb, lin_b, out_gain, out_bias, out);
}

// Round 3
// 477.503 us; speedup vs baseline: 1.0355x; 1.0355x over previous
//
#include <hip/hip_runtime.h>

// Problem constants
#define B_    512
#define D_TRF 5120
#define P_    32
#define E_    160
#define D_OUT 3000
#define PAD_  61
#define D_CL  4998
#define INV_SCALE 0.07905694150420949f   // 1/sqrt(160)
#define N_PAD 3072          // lin_w rows padded
#define WPAD 168            // LDS row stride for 160-wide weights (16B aligned)

typedef __attribute__((ext_vector_type(4))) float floatx4;
typedef __attribute__((ext_vector_type(8))) short short8;

static __device__ __forceinline__ unsigned short f2bf(float f) {
    unsigned int u = __float_as_uint(f);
    unsigned int r = (u + 0x7fffu + ((u >> 16) & 1u)) >> 16;
    return (unsigned short)r;
}
static __device__ __forceinline__ float bf2f(unsigned short u) {
    return __uint_as_float(((unsigned int)u) << 16);
}

// ---------------------------------------------------------------------------
// K0: cast lin_w [3000,5120] f32 -> [3072,5120] bf16 (pad rows zeroed)
// ---------------------------------------------------------------------------
__global__ __launch_bounds__(256) void k_castw(const float* __restrict__ w,
                                               unsigned short* __restrict__ wb) {
    size_t i4 = ((size_t)blockIdx.x * 256 + threadIdx.x) * 4;
    size_t o = i4 / D_TRF;
    ushort4 s;
    if (o < D_OUT) {
        float4 v = *(const float4*)(w + i4);
        s.x = f2bf(v.x); s.y = f2bf(v.y); s.z = f2bf(v.z); s.w = f2bf(v.w);
    } else {
        s.x = s.y = s.z = s.w = 0;
    }
    *(ushort4*)(wb + i4) = s;
}

// ---------------------------------------------------------------------------
// K0b: cast wq/wk/wv ([f][e], already B-operand layout) to bf16;
//      transpose bt_w -> wtb[f][e] = bt_w[e][f].
// ---------------------------------------------------------------------------
__global__ __launch_bounds__(256) void k_cast_small(const float* __restrict__ wq,
                                                    const float* __restrict__ wk,
                                                    const float* __restrict__ wv,
                                                    const float* __restrict__ btw,
                                                    unsigned short* __restrict__ wqb,
                                                    unsigned short* __restrict__ wkb,
                                                    unsigned short* __restrict__ wvb,
                                                    unsigned short* __restrict__ wtb) {
    int idx = blockIdx.x * 256 + threadIdx.x;   // < 25600
    wqb[idx] = f2bf(wq[idx]);
    wkb[idx] = f2bf(wk[idx]);
    wvb[idx] = f2bf(wv[idx]);
    int f = idx / E_, e = idx - f * E_;
    wtb[idx] = f2bf(btw[(size_t)e * E_ + f]);
}

// ---------------------------------------------------------------------------
// K1: cl = (x*std+mean) @ mat, with 61-zero pad both sides -> [512,5120]
// ---------------------------------------------------------------------------
__global__ __launch_bounds__(256) void k_cl(const float* __restrict__ x,
                                            const float* __restrict__ stdv,
                                            const float* __restrict__ meanv,
                                            const float* __restrict__ mat,
                                            float* __restrict__ cl) {
    int bg = blockIdx.x, jc = blockIdx.y, tid = threadIdx.x;
    __shared__ float t[8 * 64];
    for (int idx = tid; idx < 8 * 64; idx += 256) {
        int i = idx >> 6, k = idx & 63;
        t[idx] = x[(size_t)(bg * 8 + i) * 64 + k] * stdv[k] + meanv[k];
    }
    __syncthreads();

    if (jc == 0) {
        for (int idx = tid; idx < 8 * PAD_; idx += 256) {
            int i = idx / PAD_, jj = idx - i * PAD_;
            cl[(size_t)(bg * 8 + i) * D_TRF + jj] = 0.f;
        }
    } else if (jc == 3) {
        for (int idx = tid; idx < 8 * PAD_; idx += 256) {
            int i = idx / PAD_, jj = idx - i * PAD_;
            cl[(size_t)(bg * 8 + i) * D_TRF + (D_TRF - PAD_) + jj] = 0.f;
        }
    }

    int j0 = jc * 1250;
    int jend = min(D_CL, j0 + 1250);
    for (int j = j0 + tid; j < jend; j += 256) {
        float acc[8] = {};
        #pragma unroll 16
        for (int k = 0; k < 64; ++k) {
            float m = mat[(size_t)k * D_CL + j];
            #pragma unroll
            for (int i = 0; i < 8; ++i) acc[i] += t[i * 64 + k] * m;
        }
        #pragma unroll
        for (int i = 0; i < 8; ++i)
            cl[(size_t)(bg * 8 + i) * D_TRF + PAD_ + j] = acc[i];
    }
}

// ---------------------------------------------------------------------------
// K2: LayerNorm cl row -> xn bf16 [16384,160]. grid = 512 (one b each)
// ---------------------------------------------------------------------------
__global__ __launch_bounds__(256) void k_ln(const float* __restrict__ cl,
                                            const float* __restrict__ ln_g,
                                            const float* __restrict__ ln_b,
                                            unsigned short* __restrict__ xn) {
    int b = blockIdx.x, tid = threadIdx.x;
    __shared__ float redA[4], redB[4];
    __shared__ float sMu, sRstd;
    const float* row = cl + (size_t)b * D_TRF;

    float s = 0.f, s2 = 0.f;
    #pragma unroll
    for (int it = 0; it < 5; ++it) {
        int i4 = (it * 256 + tid) * 4;
        float4 v = *(const float4*)(row + i4);
        s += v.x + v.y + v.z + v.w;
        s2 += v.x * v.x + v.y * v.y + v.z * v.z + v.w * v.w;
    }
    #pragma unroll
    for (int off = 32; off; off >>= 1) {
        s  += __shfl_down(s, off);
        s2 += __shfl_down(s2, off);
    }
    if ((tid & 63) == 0) { redA[tid >> 6] = s; redB[tid >> 6] = s2; }
    __syncthreads();
    if (tid == 0) {
        float S = redA[0] + redA[1] + redA[2] + redA[3];
        float S2 = redB[0] + redB[1] + redB[2] + redB[3];
        float mu = S / (float)D_TRF;
        float var = S2 / (float)D_TRF - mu * mu;
        sMu = mu; sRstd = rsqrtf(var + 1e-5f);
    }
    __syncthreads();
    float mu = sMu, rs = sRstd;
    #pragma unroll
    for (int it = 0; it < 5; ++it) {
        int i4 = (it * 256 + tid) * 4;
        float4 v = *(const float4*)(row + i4);
        float4 g = *(const float4*)(ln_g + i4);
        float4 be = *(const float4*)(ln_b + i4);
        ushort4 o;
        o.x = f2bf((v.x - mu) * rs * g.x + be.x);
        o.y = f2bf((v.y - mu) * rs * g.y + be.y);
        o.z = f2bf((v.z - mu) * rs * g.z + be.z);
        o.w = f2bf((v.w - mu) * rs * g.w + be.w);
        *(ushort4*)(xn + (size_t)b * D_TRF + i4) = o;
    }
}

// ---------------------------------------------------------------------------
// K3: QKV via MFMA. A = xn [16384,160] bf16; B = wq/wk/wv [160,160] bf16
//     ([f][e], K-contig). grid = 256 blocks x 64 rows; 4 waves x 16 rows.
// ---------------------------------------------------------------------------
__global__ __launch_bounds__(256) void k_qkv2(const unsigned short* __restrict__ xn,
                                              const unsigned short* __restrict__ wqb,
                                              const unsigned short* __restrict__ wkb,
                                              const unsigned short* __restrict__ wvb,
                                              const float* __restrict__ bq,
                                              const float* __restrict__ bk,
                                              const float* __restrict__ bv,
                                              unsigned short* __restrict__ Qb,
                                              unsigned short* __restrict__ Kb,
                                              unsigned short* __restrict__ Vb) {
    __shared__ __align__(16) unsigned short Bs[E_ * WPAD];
    int tid = threadIdx.x, wid = tid >> 6, lane = tid & 63;
    int l16 = lane & 15, quad = lane >> 4;
    int m0 = blockIdx.x * 64 + wid * 16;

    short8 a[5];
    const unsigned short* arow = xn + (size_t)(m0 + l16) * E_ + quad * 8;
    #pragma unroll
    for (int kc = 0; kc < 5; ++kc) a[kc] = *(const short8*)(arow + kc * 32);

    const unsigned short* wsrc[3] = {wqb, wkb, wvb};
    const float* bias[3] = {bq, bk, bv};
    unsigned short* outp[3] = {Qb, Kb, Vb};

    for (int mat = 0; mat < 3; ++mat) {
        __syncthreads();
        for (int idx = tid; idx < E_ * E_; idx += 256) {
            int f = idx / E_, e = idx - f * E_;
            Bs[f * WPAD + e] = wsrc[mat][idx];
        }
        __syncthreads();
        #pragma unroll
        for (int cf = 0; cf < 10; ++cf) {
            floatx4 acc = {0.f, 0.f, 0.f, 0.f};
            const unsigned short* bp = &Bs[(cf * 16 + l16) * WPAD + quad * 8];
            #pragma unroll
            for (int kc = 0; kc < 5; ++kc) {
                short8 bf = *(const short8*)(bp + kc * 32);
                acc = __builtin_amdgcn_mfma_f32_16x16x32_bf16(a[kc], bf, acc, 0, 0, 0);
            }
            float bb = bias[mat][cf * 16 + l16];
            size_t o = (size_t)(m0 + quad * 4) * E_ + cf * 16 + l16;
            #pragma unroll
            for (int r = 0; r < 4; ++r)
                outp[mat][o + (size_t)r * E_] = f2bf(acc[r] + bb);
        }
    }
}

// ---------------------------------------------------------------------------
// K4: attention per b (bf16 QKV): dot=Q K^T/sqrt(E); softmax over dim p;
//     h = att@V + cl (f32); also x2b = bf16(h*bt_gain + bt_bias)
// ---------------------------------------------------------------------------
__global__ __launch_bounds__(256) void k_attn(const unsigned short* __restrict__ Q,
                                              const unsigned short* __restrict__ K,
                                              const unsigned short* __restrict__ V,
                                              const float* __restrict__ cl,
                                              const float* __restrict__ bt_gain,
                                              const float* __restrict__ bt_bias,
                                              float* __restrict__ h,
                                              unsigned short* __restrict__ x2b) {
    int b = blockIdx.x, tid = threadIdx.x;
    __shared__ float Qs[P_ * E_];
    __shared__ float KsT[E_ * 33];
    __shared__ float att[P_ * P_];

    const unsigned short* Qg = Q + (size_t)b * D_TRF;
    const unsigned short* Kg = K + (size_t)b * D_TRF;
    for (int idx = tid; idx < D_TRF; idx += 256) {
        Qs[idx] = bf2f(Qg[idx]);
        int q = idx / E_, e = idx - q * E_;
        KsT[e * 33 + q] = bf2f(Kg[idx]);
    }
    __syncthreads();

    for (int idx = tid; idx < P_ * P_; idx += 256) {
        int p = idx >> 5, q = idx & 31;
        const float* qrow = Qs + p * E_;
        float a = 0.f;
        #pragma unroll 8
        for (int e = 0; e < E_; ++e) a += qrow[e] * KsT[e * 33 + q];
        att[idx] = a * INV_SCALE;
    }
    __syncthreads();

    if (tid < 32) {
        int q = tid;
        float mx = -1e30f;
        #pragma unroll
        for (int p = 0; p < P_; ++p) mx = fmaxf(mx, att[p * 32 + q]);
        float sum = 0.f;
        #pragma unroll
        for (int p = 0; p < P_; ++p) {
            float e_ = expf(att[p * 32 + q] - mx);
            att[p * 32 + q] = e_;
            sum += e_;
        }
        float inv = 1.f / sum;
        #pragma unroll
        for (int p = 0; p < P_; ++p) att[p * 32 + q] *= inv;
    }
    __syncthreads();

    float gg = bt_gain[0], bb2 = bt_bias[0];
    const unsigned short* Vg = V + (size_t)b * D_TRF;
    const float* clr = cl + (size_t)b * D_TRF;
    for (int idx = tid; idx < D_TRF; idx += 256) {
        int p = idx / E_, e = idx - p * E_;
        const float* ar = att + p * 32;
        float a = 0.f;
        #pragma unroll
        for (int q = 0; q < P_; ++q) a += ar[q] * bf2f(Vg[q * E_ + e]);
        float hv = a + clr[idx];
        h[(size_t)b * D_TRF + idx] = hv;
        x2b[(size_t)b * D_TRF + idx] = f2bf(hv * gg + bb2);
    }
}

// ---------------------------------------------------------------------------
// K5: Better_Transformer via MFMA: o = x2 @ wtb + bt_b; Supact; +h -> yb
// ---------------------------------------------------------------------------
__global__ __launch_bounds__(256) void k_bt2(const unsigned short* __restrict__ x2b,
                                             const unsigned short* __restrict__ wtb,
                                             const float* __restrict__ bt_b,
                                             const float* __restrict__ sup_g,
                                             const float* __restrict__ sup_b,
                                             const float* __restrict__ h,
                                             unsigned short* __restrict__ yb) {
    __shared__ __align__(16) unsigned short Bs[E_ * WPAD];
    int tid = threadIdx.x, wid = tid >> 6, lane = tid & 63;
    int l16 = lane & 15, quad = lane >> 4;
    int m0 = blockIdx.x * 64 + wid * 16;

    short8 a[5];
    const unsigned short* arow = x2b + (size_t)(m0 + l16) * E_ + quad * 8;
    #pragma unroll
    for (int kc = 0; kc < 5; ++kc) a[kc] = *(const short8*)(arow + kc * 32);

    for (int idx = tid; idx < E_ * E_; idx += 256) {
        int f = idx / E_, e = idx - f * E_;
        Bs[f * WPAD + e] = wtb[idx];
    }
    __syncthreads();

    #pragma unroll
    for (int cf = 0; cf < 10; ++cf) {
        floatx4 acc = {0.f, 0.f, 0.f, 0.f};
        const unsigned short* bp = &Bs[(cf * 16 + l16) * WPAD + quad * 8];
        #pragma unroll
        for (int kc = 0; kc < 5; ++kc) {
            short8 bf = *(const short8*)(bp + kc * 32);
            acc = __builtin_amdgcn_mfma_f32_16x16x32_bf16(a[kc], bf, acc, 0, 0, 0);
        }
        int col = cf * 16 + l16;
        float bb = bt_b[col];
        #pragma unroll
        for (int r = 0; r < 4; ++r) {
            int row = m0 + quad * 4 + r;
            int p = row & 31;
            int i = p * E_ + col;
            float o = acc[r] + bb;
            float sig = 1.f / (1.f + expf(-sup_b[i] * o));
            float y = (sup_g[i] + sig * (1.f - sup_g[i])) * o + h[(size_t)row * E_ + col];
            yb[(size_t)row * E_ + col] = f2bf(y);
        }
    }
}

// ---------------------------------------------------------------------------
// K6: head GEMM — round-1 proven version (direct-global MFMA frags).
// Block tile 64(b) x 64(o): 4 waves (2x2), each wave 32x32 via 2x2 frags.
// ---------------------------------------------------------------------------
__global__ __launch_bounds__(256) void k_lin(const unsigned short* __restrict__ yb,
                                             const unsigned short* __restrict__ wb,
                                             const float* __restrict__ lin_b,
                                             const float* __restrict__ out_gain,
                                             const float* __restrict__ out_bias,
                                             float* __restrict__ out) {
    int ot = blockIdx.x, bt = blockIdx.y;
    int tid = threadIdx.x;
    int wid = tid >> 6, lane = tid & 63;
    int wm = wid >> 1, wn = wid & 1;
    int l16 = lane & 15, quad = lane >> 4;

    int b_base = bt * 64 + wm * 32;
    int o_base = ot * 64 + wn * 32;

    size_t aoff0 = (size_t)(b_base + l16) * D_TRF + quad * 8;
    size_t aoff1 = aoff0 + (size_t)16 * D_TRF;
    size_t boff0 = (size_t)(o_base + l16) * D_TRF + quad * 8;
    size_t boff1 = boff0 + (size_t)16 * D_TRF;

    floatx4 acc00 = {0.f, 0.f, 0.f, 0.f};
    floatx4 acc01 = {0.f, 0.f, 0.f, 0.f};
    floatx4 acc10 = {0.f, 0.f, 0.f, 0.f};
    floatx4 acc11 = {0.f, 0.f, 0.f, 0.f};

    for (int k0 = 0; k0 < D_TRF; k0 += 32) {
        short8 a0 = *(const short8*)(yb + aoff0 + k0);
        short8 a1 = *(const short8*)(yb + aoff1 + k0);
        short8 b0 = *(const short8*)(wb + boff0 + k0);
        short8 b1 = *(const short8*)(wb + boff1 + k0);
        acc00 = __builtin_amdgcn_mfma_f32_16x16x32_bf16(a0, b0, acc00, 0, 0, 0);
        acc01 = __builtin_amdgcn_mfma_f32_16x16x32_bf16(a0, b1, acc01, 0, 0, 0);
        acc10 = __builtin_amdgcn_mfma_f32_16x16x32_bf16(a1, b0, acc10, 0, 0, 0);
        acc11 = __builtin_amdgcn_mfma_f32_16x16x32_bf16(a1, b1, acc11, 0, 0, 0);
    }

    float g = out_gain[0], ob = out_bias[0];
    floatx4 accs[2][2] = {{acc00, acc01}, {acc10, acc11}};
    #pragma unroll
    for (int i = 0; i < 2; ++i) {
        int brow = b_base + i * 16 + quad * 4;
        #pragma unroll
        for (int j = 0; j < 2; ++j) {
            int ocol = o_base + j * 16 + l16;
            if (ocol >= D_OUT) continue;
            float cadd = lin_b[ocol] * g + ob;
            #pragma unroll
            for (int r = 0; r < 4; ++r)
                out[(size_t)(brow + r) * D_OUT + ocol] = accs[i][j][r] * g + cadd;
        }
    }
}

// ---------------------------------------------------------------------------
// Workspace layout (bytes)
// ---------------------------------------------------------------------------
#define SZ_ROWF ((size_t)B_ * D_TRF * 4)           // 10,485,760
#define SZ_ROWB ((size_t)B_ * D_TRF * 2)           // 5,242,880
#define OFF_CL  ((size_t)0)
#define OFF_H   (OFF_CL + SZ_ROWF)
#define OFF_XN  (OFF_H + SZ_ROWF)                  // xn bf16; reused as x2b
#define OFF_QB  (OFF_XN + SZ_ROWB)
#define OFF_KB  (OFF_QB + SZ_ROWB)
#define OFF_VB  (OFF_KB + SZ_ROWB)
#define OFF_YB  (OFF_VB + SZ_ROWB)
#define OFF_WSM (OFF_YB + SZ_ROWB)                 // 4 x 51200 B
#define OFF_WB  (OFF_WSM + (size_t)4 * E_ * E_ * 2)
// end = OFF_WB + 3072*5120*2 = 78,848,000 bytes

extern "C" void kernel_launch(void* const* d_in, const int* in_sizes, int n_in,
                              void* d_out, int out_size, void* d_ws, size_t ws_size,
                              hipStream_t stream) {
    const float* x        = (const float*)d_in[0];
    const float* stdv     = (const float*)d_in[1];
    const float* meanv    = (const float*)d_in[2];
    const float* mat      = (const float*)d_in[3];
    const float* ln_g     = (const float*)d_in[4];
    const float* ln_b     = (const float*)d_in[5];
    const float* wq       = (const float*)d_in[6];
    const float* bq       = (const float*)d_in[7];
    const float* wk       = (const float*)d_in[8];
    const float* bk       = (const float*)d_in[9];
    const float* wv       = (const float*)d_in[10];
    const float* bv       = (const float*)d_in[11];
    const float* bt_w     = (const float*)d_in[12];
    const float* bt_b     = (const float*)d_in[13];
    const float* bt_gain  = (const float*)d_in[14];
    const float* bt_bias  = (const float*)d_in[15];
    const float* sup_g    = (const float*)d_in[16];
    const float* sup_b    = (const float*)d_in[17];
    const float* lin_w    = (const float*)d_in[18];
    const float* lin_b    = (const float*)d_in[19];
    const float* out_gain = (const float*)d_in[20];
    const float* out_bias = (const float*)d_in[21];

    char* ws = (char*)d_ws;
    float* cl = (float*)(ws + OFF_CL);
    float* h  = (float*)(ws + OFF_H);
    unsigned short* xn  = (unsigned short*)(ws + OFF_XN);
    unsigned short* x2b = xn;   // xn dead after k_qkv2
    unsigned short* Qb  = (unsigned short*)(ws + OFF_QB);
    unsigned short* Kb  = (unsigned short*)(ws + OFF_KB);
    unsigned short* Vb  = (unsigned short*)(ws + OFF_VB);
    unsigned short* yb  = (unsigned short*)(ws + OFF_YB);
    unsigned short* wqb = (unsigned short*)(ws + OFF_WSM);
    unsigned short* wkb = wqb + E_ * E_;
    unsigned short* wvb = wkb + E_ * E_;
    unsigned short* wtb = wvb + E_ * E_;
    unsigned short* wb  = (unsigned short*)(ws + OFF_WB);
    float* out = (float*)d_out;

    k_castw<<<15360, 256, 0, stream>>>(lin_w, wb);
    k_cast_small<<<100, 256, 0, stream>>>(wq, wk, wv, bt_w, wqb, wkb, wvb, wtb);
    k_cl<<<dim3(64, 4), 256, 0, stream>>>(x, stdv, meanv, mat, cl);
    k_ln<<<512, 256, 0, stream>>>(cl, ln_g, ln_b, xn);
    k_qkv2<<<256, 256, 0, stream>>>(xn, wqb, wkb, wvb, bq, bk, bv, Qb, Kb, Vb);
    k_attn<<<512, 256, 0, stream>>>(Qb, Kb, Vb, cl, bt_gain, bt_bias, h, x2b);
    k_bt2<<<256, 256, 0, stream>>>(x2b, wtb, bt_b, sup_g, sup_b, h, yb);
    k_lin<<<dim3(47, 8), 256, 0, stream>>>(yb, wb, lin_b, out_gain, out_bias, out);
}

// Round 4
// 395.289 us; speedup vs baseline: 1.2508x; 1.2080x over previous
//
#include <hip/hip_runtime.h>

// Problem constants
#define B_    512
#define D_TRF 5120
#define P_    32
#define E_    160
#define D_OUT 3000
#define PAD_  61
#define D_CL  4998
#define INV_SCALE 0.07905694150420949f   // 1/sqrt(160)
#define N_PAD 3072          // lin_w rows padded (32 tiles of 96)
#define WPAD 168            // LDS row stride for 160-wide weights (16B aligned)

typedef __attribute__((ext_vector_type(4))) float floatx4;
typedef __attribute__((ext_vector_type(8))) short short8;

static __device__ __forceinline__ unsigned short f2bf(float f) {
    unsigned int u = __float_as_uint(f);
    unsigned int r = (u + 0x7fffu + ((u >> 16) & 1u)) >> 16;
    return (unsigned short)r;
}
static __device__ __forceinline__ float bf2f(unsigned short u) {
    return __uint_as_float(((unsigned int)u) << 16);
}
static __device__ __forceinline__ void load_lds16(const void* g, void* lds) {
    __builtin_amdgcn_global_load_lds(
        (const __attribute__((address_space(1))) unsigned int*)g,
        (__attribute__((address_space(3))) unsigned int*)lds, 16, 0, 0);
}

// ---------------------------------------------------------------------------
// K0: cast lin_w [3000,5120] f32 -> [3072,5120] bf16 (pad rows zeroed)
// ---------------------------------------------------------------------------
__global__ __launch_bounds__(256) void k_castw(const float* __restrict__ w,
                                               unsigned short* __restrict__ wb) {
    size_t i4 = ((size_t)blockIdx.x * 256 + threadIdx.x) * 4;
    size_t o = i4 / D_TRF;
    ushort4 s;
    if (o < D_OUT) {
        float4 v = *(const float4*)(w + i4);
        s.x = f2bf(v.x); s.y = f2bf(v.y); s.z = f2bf(v.z); s.w = f2bf(v.w);
    } else {
        s.x = s.y = s.z = s.w = 0;
    }
    *(ushort4*)(wb + i4) = s;
}

// ---------------------------------------------------------------------------
// K0b: cast wq/wk/wv ([f][e], already B-operand layout) to bf16;
//      transpose bt_w -> wtb[f][e] = bt_w[e][f].
// ---------------------------------------------------------------------------
__global__ __launch_bounds__(256) void k_cast_small(const float* __restrict__ wq,
                                                    const float* __restrict__ wk,
                                                    const float* __restrict__ wv,
                                                    const float* __restrict__ btw,
                                                    unsigned short* __restrict__ wqb,
                                                    unsigned short* __restrict__ wkb,
                                                    unsigned short* __restrict__ wvb,
                                                    unsigned short* __restrict__ wtb) {
    int idx = blockIdx.x * 256 + threadIdx.x;   // < 25600
    wqb[idx] = f2bf(wq[idx]);
    wkb[idx] = f2bf(wk[idx]);
    wvb[idx] = f2bf(wv[idx]);
    int f = idx / E_, e = idx - f * E_;
    wtb[idx] = f2bf(btw[(size_t)e * E_ + f]);
}

// ---------------------------------------------------------------------------
// K1: cl = (x*std+mean) @ mat, with 61-zero pad both sides -> [512,5120]
// ---------------------------------------------------------------------------
__global__ __launch_bounds__(256) void k_cl(const float* __restrict__ x,
                                            const float* __restrict__ stdv,
                                            const float* __restrict__ meanv,
                                            const float* __restrict__ mat,
                                            float* __restrict__ cl) {
    int bg = blockIdx.x, jc = blockIdx.y, tid = threadIdx.x;
    __shared__ float t[8 * 64];
    for (int idx = tid; idx < 8 * 64; idx += 256) {
        int i = idx >> 6, k = idx & 63;
        t[idx] = x[(size_t)(bg * 8 + i) * 64 + k] * stdv[k] + meanv[k];
    }
    __syncthreads();

    if (jc == 0) {
        for (int idx = tid; idx < 8 * PAD_; idx += 256) {
            int i = idx / PAD_, jj = idx - i * PAD_;
            cl[(size_t)(bg * 8 + i) * D_TRF + jj] = 0.f;
        }
    } else if (jc == 3) {
        for (int idx = tid; idx < 8 * PAD_; idx += 256) {
            int i = idx / PAD_, jj = idx - i * PAD_;
            cl[(size_t)(bg * 8 + i) * D_TRF + (D_TRF - PAD_) + jj] = 0.f;
        }
    }

    int j0 = jc * 1250;
    int jend = min(D_CL, j0 + 1250);
    for (int j = j0 + tid; j < jend; j += 256) {
        float acc[8] = {};
        #pragma unroll 16
        for (int k = 0; k < 64; ++k) {
            float m = mat[(size_t)k * D_CL + j];
            #pragma unroll
            for (int i = 0; i < 8; ++i) acc[i] += t[i * 64 + k] * m;
        }
        #pragma unroll
        for (int i = 0; i < 8; ++i)
            cl[(size_t)(bg * 8 + i) * D_TRF + PAD_ + j] = acc[i];
    }
}

// ---------------------------------------------------------------------------
// K2: LayerNorm cl row -> xn bf16 [16384,160]. grid = 512 (one b each)
// ---------------------------------------------------------------------------
__global__ __launch_bounds__(256) void k_ln(const float* __restrict__ cl,
                                            const float* __restrict__ ln_g,
                                            const float* __restrict__ ln_b,
                                            unsigned short* __restrict__ xn) {
    int b = blockIdx.x, tid = threadIdx.x;
    __shared__ float redA[4], redB[4];
    __shared__ float sMu, sRstd;
    const float* row = cl + (size_t)b * D_TRF;

    float s = 0.f, s2 = 0.f;
    #pragma unroll
    for (int it = 0; it < 5; ++it) {
        int i4 = (it * 256 + tid) * 4;
        float4 v = *(const float4*)(row + i4);
        s += v.x + v.y + v.z + v.w;
        s2 += v.x * v.x + v.y * v.y + v.z * v.z + v.w * v.w;
    }
    #pragma unroll
    for (int off = 32; off; off >>= 1) {
        s  += __shfl_down(s, off);
        s2 += __shfl_down(s2, off);
    }
    if ((tid & 63) == 0) { redA[tid >> 6] = s; redB[tid >> 6] = s2; }
    __syncthreads();
    if (tid == 0) {
        float S = redA[0] + redA[1] + redA[2] + redA[3];
        float S2 = redB[0] + redB[1] + redB[2] + redB[3];
        float mu = S / (float)D_TRF;
        float var = S2 / (float)D_TRF - mu * mu;
        sMu = mu; sRstd = rsqrtf(var + 1e-5f);
    }
    __syncthreads();
    float mu = sMu, rs = sRstd;
    #pragma unroll
    for (int it = 0; it < 5; ++it) {
        int i4 = (it * 256 + tid) * 4;
        float4 v = *(const float4*)(row + i4);
        float4 g = *(const float4*)(ln_g + i4);
        float4 be = *(const float4*)(ln_b + i4);
        ushort4 o;
        o.x = f2bf((v.x - mu) * rs * g.x + be.x);
        o.y = f2bf((v.y - mu) * rs * g.y + be.y);
        o.z = f2bf((v.z - mu) * rs * g.z + be.z);
        o.w = f2bf((v.w - mu) * rs * g.w + be.w);
        *(ushort4*)(xn + (size_t)b * D_TRF + i4) = o;
    }
}

// ---------------------------------------------------------------------------
// K3: QKV via MFMA. A = xn [16384,160] bf16; B = wq/wk/wv [160,160] bf16
// ---------------------------------------------------------------------------
__global__ __launch_bounds__(256) void k_qkv2(const unsigned short* __restrict__ xn,
                                              const unsigned short* __restrict__ wqb,
                                              const unsigned short* __restrict__ wkb,
                                              const unsigned short* __restrict__ wvb,
                                              const float* __restrict__ bq,
                                              const float* __restrict__ bk,
                                              const float* __restrict__ bv,
                                              unsigned short* __restrict__ Qb,
                                              unsigned short* __restrict__ Kb,
                                              unsigned short* __restrict__ Vb) {
    __shared__ __align__(16) unsigned short Bs[E_ * WPAD];
    int tid = threadIdx.x, wid = tid >> 6, lane = tid & 63;
    int l16 = lane & 15, quad = lane >> 4;
    int m0 = blockIdx.x * 64 + wid * 16;

    short8 a[5];
    const unsigned short* arow = xn + (size_t)(m0 + l16) * E_ + quad * 8;
    #pragma unroll
    for (int kc = 0; kc < 5; ++kc) a[kc] = *(const short8*)(arow + kc * 32);

    const unsigned short* wsrc[3] = {wqb, wkb, wvb};
    const float* bias[3] = {bq, bk, bv};
    unsigned short* outp[3] = {Qb, Kb, Vb};

    for (int mat = 0; mat < 3; ++mat) {
        __syncthreads();
        for (int idx = tid; idx < E_ * E_; idx += 256) {
            int f = idx / E_, e = idx - f * E_;
            Bs[f * WPAD + e] = wsrc[mat][idx];
        }
        __syncthreads();
        #pragma unroll
        for (int cf = 0; cf < 10; ++cf) {
            floatx4 acc = {0.f, 0.f, 0.f, 0.f};
            const unsigned short* bp = &Bs[(cf * 16 + l16) * WPAD + quad * 8];
            #pragma unroll
            for (int kc = 0; kc < 5; ++kc) {
                short8 bf = *(const short8*)(bp + kc * 32);
                acc = __builtin_amdgcn_mfma_f32_16x16x32_bf16(a[kc], bf, acc, 0, 0, 0);
            }
            float bb = bias[mat][cf * 16 + l16];
            size_t o = (size_t)(m0 + quad * 4) * E_ + cf * 16 + l16;
            #pragma unroll
            for (int r = 0; r < 4; ++r)
                outp[mat][o + (size_t)r * E_] = f2bf(acc[r] + bb);
        }
    }
}

// ---------------------------------------------------------------------------
// K4: attention per b (bf16 QKV): dot=Q K^T/sqrt(E); softmax over dim p;
//     h = att@V + cl (f32); also x2b = bf16(h*bt_gain + bt_bias)
// ---------------------------------------------------------------------------
__global__ __launch_bounds__(256) void k_attn(const unsigned short* __restrict__ Q,
                                              const unsigned short* __restrict__ K,
                                              const unsigned short* __restrict__ V,
                                              const float* __restrict__ cl,
                                              const float* __restrict__ bt_gain,
                                              const float* __restrict__ bt_bias,
                                              float* __restrict__ h,
                                              unsigned short* __restrict__ x2b) {
    int b = blockIdx.x, tid = threadIdx.x;
    __shared__ float Qs[P_ * E_];
    __shared__ float KsT[E_ * 33];
    __shared__ float att[P_ * P_];

    const unsigned short* Qg = Q + (size_t)b * D_TRF;
    const unsigned short* Kg = K + (size_t)b * D_TRF;
    for (int idx = tid; idx < D_TRF; idx += 256) {
        Qs[idx] = bf2f(Qg[idx]);
        int q = idx / E_, e = idx - q * E_;
        KsT[e * 33 + q] = bf2f(Kg[idx]);
    }
    __syncthreads();

    for (int idx = tid; idx < P_ * P_; idx += 256) {
        int p = idx >> 5, q = idx & 31;
        const float* qrow = Qs + p * E_;
        float a = 0.f;
        #pragma unroll 8
        for (int e = 0; e < E_; ++e) a += qrow[e] * KsT[e * 33 + q];
        att[idx] = a * INV_SCALE;
    }
    __syncthreads();

    if (tid < 32) {
        int q = tid;
        float mx = -1e30f;
        #pragma unroll
        for (int p = 0; p < P_; ++p) mx = fmaxf(mx, att[p * 32 + q]);
        float sum = 0.f;
        #pragma unroll
        for (int p = 0; p < P_; ++p) {
            float e_ = expf(att[p * 32 + q] - mx);
            att[p * 32 + q] = e_;
            sum += e_;
        }
        float inv = 1.f / sum;
        #pragma unroll
        for (int p = 0; p < P_; ++p) att[p * 32 + q] *= inv;
    }
    __syncthreads();

    float gg = bt_gain[0], bb2 = bt_bias[0];
    const unsigned short* Vg = V + (size_t)b * D_TRF;
    const float* clr = cl + (size_t)b * D_TRF;
    for (int idx = tid; idx < D_TRF; idx += 256) {
        int p = idx / E_, e = idx - p * E_;
        const float* ar = att + p * 32;
        float a = 0.f;
        #pragma unroll
        for (int q = 0; q < P_; ++q) a += ar[q] * bf2f(Vg[q * E_ + e]);
        float hv = a + clr[idx];
        h[(size_t)b * D_TRF + idx] = hv;
        x2b[(size_t)b * D_TRF + idx] = f2bf(hv * gg + bb2);
    }
}

// ---------------------------------------------------------------------------
// K5: Better_Transformer via MFMA: o = x2 @ wtb + bt_b; Supact; +h -> yb
// ---------------------------------------------------------------------------
__global__ __launch_bounds__(256) void k_bt2(const unsigned short* __restrict__ x2b,
                                             const unsigned short* __restrict__ wtb,
                                             const float* __restrict__ bt_b,
                                             const float* __restrict__ sup_g,
                                             const float* __restrict__ sup_b,
                                             const float* __restrict__ h,
                                             unsigned short* __restrict__ yb) {
    __shared__ __align__(16) unsigned short Bs[E_ * WPAD];
    int tid = threadIdx.x, wid = tid >> 6, lane = tid & 63;
    int l16 = lane & 15, quad = lane >> 4;
    int m0 = blockIdx.x * 64 + wid * 16;

    short8 a[5];
    const unsigned short* arow = x2b + (size_t)(m0 + l16) * E_ + quad * 8;
    #pragma unroll
    for (int kc = 0; kc < 5; ++kc) a[kc] = *(const short8*)(arow + kc * 32);

    for (int idx = tid; idx < E_ * E_; idx += 256) {
        int f = idx / E_, e = idx - f * E_;
        Bs[f * WPAD + e] = wtb[idx];
    }
    __syncthreads();

    #pragma unroll
    for (int cf = 0; cf < 10; ++cf) {
        floatx4 acc = {0.f, 0.f, 0.f, 0.f};
        const unsigned short* bp = &Bs[(cf * 16 + l16) * WPAD + quad * 8];
        #pragma unroll
        for (int kc = 0; kc < 5; ++kc) {
            short8 bf = *(const short8*)(bp + kc * 32);
            acc = __builtin_amdgcn_mfma_f32_16x16x32_bf16(a[kc], bf, acc, 0, 0, 0);
        }
        int col = cf * 16 + l16;
        float bb = bt_b[col];
        #pragma unroll
        for (int r = 0; r < 4; ++r) {
            int row = m0 + quad * 4 + r;
            int p = row & 31;
            int i = p * E_ + col;
            float o = acc[r] + bb;
            float sig = 1.f / (1.f + expf(-sup_b[i] * o));
            float y = (sup_g[i] + sig * (1.f - sup_g[i])) * o + h[(size_t)row * E_ + col];
            yb[(size_t)row * E_ + col] = f2bf(y);
        }
    }
}

// ---------------------------------------------------------------------------
// K6: init out with bias terms: out[row,col] = lin_b[col]*g + ob
// ---------------------------------------------------------------------------
__global__ __launch_bounds__(256) void k_init_out(const float* __restrict__ lin_b,
                                                  const float* __restrict__ out_gain,
                                                  const float* __restrict__ out_bias,
                                                  float* __restrict__ out) {
    int col = blockIdx.x * 256 + threadIdx.x;
    if (col >= D_OUT) return;
    out[(size_t)blockIdx.y * D_OUT + col] = lin_b[col] * out_gain[0] + out_bias[0];
}

// ---------------------------------------------------------------------------
// K7: head GEMM, staged. Tile 128(m) x 96(n), BK=32, split-K=2.
// grid 256 = 32 n x 4 m x 2 sp. 4 waves 2x2, wave tile 64x48 (4x3 frags).
// LDS staging via global_load_lds (16B/lane, wave-contiguous dest slots):
//   A tile 128x32 = 512 slots: insts u=tid, u=tid+256
//   B tile  96x32 = 384 slots: insts u=tid (all), u=tid+128 (waves 2,3 only)
//   [round-2 bug was here: slots 256..383 were never staged]
// atomicAdd epilogue onto bias-initialized out.
// ---------------------------------------------------------------------------
__global__ __launch_bounds__(256) void k_lin2(const unsigned short* __restrict__ yb,
                                              const unsigned short* __restrict__ wb,
                                              const float* __restrict__ out_gain,
                                              float* __restrict__ out) {
    __shared__ __align__(16) unsigned short As[128 * 32];
    __shared__ __align__(16) unsigned short Bs[96 * 32];
    int blk = blockIdx.x;
    int n = blk & 31, mt = (blk >> 5) & 3, sp = blk >> 7;
    int tid = threadIdx.x, wid = tid >> 6, lane = tid & 63;
    int wm = wid >> 1, wn = wid & 1;
    int l16 = lane & 15, quad = lane >> 4;
    int m_base = mt * 128;

    const unsigned short* Abase = yb + (size_t)m_base * D_TRF;
    const unsigned short* Bbase = wb + (size_t)(n * 96) * D_TRF;

    // slot u -> row = u>>2, koff = (u&3)*8 ; LDS = tile[row*32 + koff]
    int uA0 = tid, uA1 = tid + 256;
    int uB0 = tid, uB1 = tid + 128;          // uB1 used by waves 2,3 only

    floatx4 acc[4][3];
    #pragma unroll
    for (int i = 0; i < 4; ++i)
        #pragma unroll
        for (int j = 0; j < 3; ++j) acc[i][j] = (floatx4){0.f, 0.f, 0.f, 0.f};

    int k0 = sp * (D_TRF / 2);
    for (int kk = 0; kk < D_TRF / 2; kk += 32) {
        int k = k0 + kk;
        load_lds16(Abase + (size_t)(uA0 >> 2) * D_TRF + k + (uA0 & 3) * 8, &As[uA0 * 8]);
        load_lds16(Abase + (size_t)(uA1 >> 2) * D_TRF + k + (uA1 & 3) * 8, &As[uA1 * 8]);
        load_lds16(Bbase + (size_t)(uB0 >> 2) * D_TRF + k + (uB0 & 3) * 8, &Bs[uB0 * 8]);
        if (wid >= 2)
            load_lds16(Bbase + (size_t)(uB1 >> 2) * D_TRF + k + (uB1 & 3) * 8, &Bs[uB1 * 8]);
        __syncthreads();

        short8 af[4], bf[3];
        #pragma unroll
        for (int fi = 0; fi < 4; ++fi)
            af[fi] = *(const short8*)(&As[(wm * 64 + fi * 16 + l16) * 32 + quad * 8]);
        #pragma unroll
        for (int fj = 0; fj < 3; ++fj)
            bf[fj] = *(const short8*)(&Bs[(wn * 48 + fj * 16 + l16) * 32 + quad * 8]);
        #pragma unroll
        for (int fi = 0; fi < 4; ++fi)
            #pragma unroll
            for (int fj = 0; fj < 3; ++fj)
                acc[fi][fj] = __builtin_amdgcn_mfma_f32_16x16x32_bf16(af[fi], bf[fj], acc[fi][fj], 0, 0, 0);
        __syncthreads();
    }

    float g = out_gain[0];
    #pragma unroll
    for (int fi = 0; fi < 4; ++fi) {
        int row = m_base + wm * 64 + fi * 16 + quad * 4;
        #pragma unroll
        for (int fj = 0; fj < 3; ++fj) {
            int col = n * 96 + wn * 48 + fj * 16 + l16;
            if (col >= D_OUT) continue;
            #pragma unroll
            for (int r = 0; r < 4; ++r)
                atomicAdd(&out[(size_t)(row + r) * D_OUT + col], acc[fi][fj][r] * g);
        }
    }
}

// ---------------------------------------------------------------------------
// Workspace layout (bytes)
// ---------------------------------------------------------------------------
#define SZ_ROWF ((size_t)B_ * D_TRF * 4)           // 10,485,760
#define SZ_ROWB ((size_t)B_ * D_TRF * 2)           // 5,242,880
#define OFF_CL  ((size_t)0)
#define OFF_H   (OFF_CL + SZ_ROWF)
#define OFF_XN  (OFF_H + SZ_ROWF)                  // xn bf16; reused as x2b
#define OFF_QB  (OFF_XN + SZ_ROWB)
#define OFF_KB  (OFF_QB + SZ_ROWB)
#define OFF_VB  (OFF_KB + SZ_ROWB)
#define OFF_YB  (OFF_VB + SZ_ROWB)
#define OFF_WSM (OFF_YB + SZ_ROWB)                 // 4 x 51200 B
#define OFF_WB  (OFF_WSM + (size_t)4 * E_ * E_ * 2)
// end = OFF_WB + 3072*5120*2 = 78,848,000 bytes

extern "C" void kernel_launch(void* const* d_in, const int* in_sizes, int n_in,
                              void* d_out, int out_size, void* d_ws, size_t ws_size,
                              hipStream_t stream) {
    const float* x        = (const float*)d_in[0];
    const float* stdv     = (const float*)d_in[1];
    const float* meanv    = (const float*)d_in[2];
    const float* mat      = (const float*)d_in[3];
    const float* ln_g     = (const float*)d_in[4];
    const float* ln_b     = (const float*)d_in[5];
    const float* wq       = (const float*)d_in[6];
    const float* bq       = (const float*)d_in[7];
    const float* wk       = (const float*)d_in[8];
    const float* bk       = (const float*)d_in[9];
    const float* wv       = (const float*)d_in[10];
    const float* bv       = (const float*)d_in[11];
    const float* bt_w     = (const float*)d_in[12];
    const float* bt_b     = (const float*)d_in[13];
    const float* bt_gain  = (const float*)d_in[14];
    const float* bt_bias  = (const float*)d_in[15];
    const float* sup_g    = (const float*)d_in[16];
    const float* sup_b    = (const float*)d_in[17];
    const float* lin_w    = (const float*)d_in[18];
    const float* lin_b    = (const float*)d_in[19];
    const float* out_gain = (const float*)d_in[20];
    const float* out_bias = (const float*)d_in[21];

    char* ws = (char*)d_ws;
    float* cl = (float*)(ws + OFF_CL);
    float* h  = (float*)(ws + OFF_H);
    unsigned short* xn  = (unsigned short*)(ws + OFF_XN);
    unsigned short* x2b = xn;   // xn dead after k_qkv2
    unsigned short* Qb  = (unsigned short*)(ws + OFF_QB);
    unsigned short* Kb  = (unsigned short*)(ws + OFF_KB);
    unsigned short* Vb  = (unsigned short*)(ws + OFF_VB);
    unsigned short* yb  = (unsigned short*)(ws + OFF_YB);
    unsigned short* wqb = (unsigned short*)(ws + OFF_WSM);
    unsigned short* wkb = wqb + E_ * E_;
    unsigned short* wvb = wkb + E_ * E_;
    unsigned short* wtb = wvb + E_ * E_;
    unsigned short* wb  = (unsigned short*)(ws + OFF_WB);
    float* out = (float*)d_out;

    k_castw<<<15360, 256, 0, stream>>>(lin_w, wb);
    k_cast_small<<<100, 256, 0, stream>>>(wq, wk, wv, bt_w, wqb, wkb, wvb, wtb);
    k_cl<<<dim3(64, 4), 256, 0, stream>>>(x, stdv, meanv, mat, cl);
    k_ln<<<512, 256, 0, stream>>>(cl, ln_g, ln_b, xn);
    k_qkv2<<<256, 256, 0, stream>>>(xn, wqb, wkb, wvb, bq, bk, bv, Qb, Kb, Vb);
    k_attn<<<512, 256, 0, stream>>>(Qb, Kb, Vb, cl, bt_gain, bt_bias, h, x2b);
    k_bt2<<<256, 256, 0, stream>>>(x2b, wtb, bt_b, sup_g, sup_b, h, yb);
    k_init_out<<<dim3(12, B_), 256, 0, stream>>>(lin_b, out_gain, out_bias, out);
    k_lin2<<<256, 256, 0, stream>>>(yb, wb, out_gain, out);
}

// Round 5
// 343.169 us; speedup vs baseline: 1.4408x; 1.1519x over previous
//
#include <hip/hip_runtime.h>

// Problem constants
#define B_    512
#define D_TRF 5120
#define P_    32
#define E_    160
#define D_OUT 3000
#define PAD_  61
#define D_CL  4998
#define INV_SCALE 0.07905694150420949f   // 1/sqrt(160)
#define N_PAD 3072          // lin_w rows padded (32 tiles of 96)

typedef __attribute__((ext_vector_type(4))) float floatx4;
typedef __attribute__((ext_vector_type(8))) short short8;

static __device__ __forceinline__ unsigned short f2bf(float f) {
    unsigned int u = __float_as_uint(f);
    unsigned int r = (u + 0x7fffu + ((u >> 16) & 1u)) >> 16;
    return (unsigned short)r;
}
static __device__ __forceinline__ float bf2f(unsigned short u) {
    return __uint_as_float(((unsigned int)u) << 16);
}
static __device__ __forceinline__ void load_lds16(const void* g, void* lds) {
    __builtin_amdgcn_global_load_lds(
        (const __attribute__((address_space(1))) unsigned int*)g,
        (__attribute__((address_space(3))) unsigned int*)lds, 16, 0, 0);
}

// ---------------------------------------------------------------------------
// K0: cast lin_w [3000,5120] f32 -> [3072,5120] bf16 (pad rows zeroed)
// ---------------------------------------------------------------------------
__global__ __launch_bounds__(256) void k_castw(const float* __restrict__ w,
                                               unsigned short* __restrict__ wb) {
    size_t i4 = ((size_t)blockIdx.x * 256 + threadIdx.x) * 4;
    size_t o = i4 / D_TRF;
    ushort4 s;
    if (o < D_OUT) {
        float4 v = *(const float4*)(w + i4);
        s.x = f2bf(v.x); s.y = f2bf(v.y); s.z = f2bf(v.z); s.w = f2bf(v.w);
    } else {
        s.x = s.y = s.z = s.w = 0;
    }
    *(ushort4*)(wb + i4) = s;
}

// ---------------------------------------------------------------------------
// K0b: cast wq/wk/wv ([f][e], already B-operand layout) to bf16;
//      transpose bt_w -> wtb[f][e] = bt_w[e][f].
// ---------------------------------------------------------------------------
__global__ __launch_bounds__(256) void k_cast_small(const float* __restrict__ wq,
                                                    const float* __restrict__ wk,
                                                    const float* __restrict__ wv,
                                                    const float* __restrict__ btw,
                                                    unsigned short* __restrict__ wqb,
                                                    unsigned short* __restrict__ wkb,
                                                    unsigned short* __restrict__ wvb,
                                                    unsigned short* __restrict__ wtb) {
    int idx = blockIdx.x * 256 + threadIdx.x;   // < 25600
    wqb[idx] = f2bf(wq[idx]);
    wkb[idx] = f2bf(wk[idx]);
    wvb[idx] = f2bf(wv[idx]);
    int f = idx / E_, e = idx - f * E_;
    wtb[idx] = f2bf(btw[(size_t)e * E_ + f]);
}

// ---------------------------------------------------------------------------
// K1: cl = (x*std+mean) @ mat, with 61-zero pad both sides -> [512,5120]
// ---------------------------------------------------------------------------
__global__ __launch_bounds__(256) void k_cl(const float* __restrict__ x,
                                            const float* __restrict__ stdv,
                                            const float* __restrict__ meanv,
                                            const float* __restrict__ mat,
                                            float* __restrict__ cl) {
    int bg = blockIdx.x, jc = blockIdx.y, tid = threadIdx.x;
    __shared__ float t[8 * 64];
    for (int idx = tid; idx < 8 * 64; idx += 256) {
        int i = idx >> 6, k = idx & 63;
        t[idx] = x[(size_t)(bg * 8 + i) * 64 + k] * stdv[k] + meanv[k];
    }
    __syncthreads();

    if (jc == 0) {
        for (int idx = tid; idx < 8 * PAD_; idx += 256) {
            int i = idx / PAD_, jj = idx - i * PAD_;
            cl[(size_t)(bg * 8 + i) * D_TRF + jj] = 0.f;
        }
    } else if (jc == 3) {
        for (int idx = tid; idx < 8 * PAD_; idx += 256) {
            int i = idx / PAD_, jj = idx - i * PAD_;
            cl[(size_t)(bg * 8 + i) * D_TRF + (D_TRF - PAD_) + jj] = 0.f;
        }
    }

    int j0 = jc * 1250;
    int jend = min(D_CL, j0 + 1250);
    for (int j = j0 + tid; j < jend; j += 256) {
        float acc[8] = {};
        #pragma unroll 16
        for (int k = 0; k < 64; ++k) {
            float m = mat[(size_t)k * D_CL + j];
            #pragma unroll
            for (int i = 0; i < 8; ++i) acc[i] += t[i * 64 + k] * m;
        }
        #pragma unroll
        for (int i = 0; i < 8; ++i)
            cl[(size_t)(bg * 8 + i) * D_TRF + PAD_ + j] = acc[i];
    }
}

// ---------------------------------------------------------------------------
// K2: LayerNorm cl row -> xn bf16 [16384,160]. grid = 512 (one b each)
// ---------------------------------------------------------------------------
__global__ __launch_bounds__(256) void k_ln(const float* __restrict__ cl,
                                            const float* __restrict__ ln_g,
                                            const float* __restrict__ ln_b,
                                            unsigned short* __restrict__ xn) {
    int b = blockIdx.x, tid = threadIdx.x;
    __shared__ float redA[4], redB[4];
    __shared__ float sMu, sRstd;
    const float* row = cl + (size_t)b * D_TRF;

    float s = 0.f, s2 = 0.f;
    #pragma unroll
    for (int it = 0; it < 5; ++it) {
        int i4 = (it * 256 + tid) * 4;
        float4 v = *(const float4*)(row + i4);
        s += v.x + v.y + v.z + v.w;
        s2 += v.x * v.x + v.y * v.y + v.z * v.z + v.w * v.w;
    }
    #pragma unroll
    for (int off = 32; off; off >>= 1) {
        s  += __shfl_down(s, off);
        s2 += __shfl_down(s2, off);
    }
    if ((tid & 63) == 0) { redA[tid >> 6] = s; redB[tid >> 6] = s2; }
    __syncthreads();
    if (tid == 0) {
        float S = redA[0] + redA[1] + redA[2] + redA[3];
        float S2 = redB[0] + redB[1] + redB[2] + redB[3];
        float mu = S / (float)D_TRF;
        float var = S2 / (float)D_TRF - mu * mu;
        sMu = mu; sRstd = rsqrtf(var + 1e-5f);
    }
    __syncthreads();
    float mu = sMu, rs = sRstd;
    #pragma unroll
    for (int it = 0; it < 5; ++it) {
        int i4 = (it * 256 + tid) * 4;
        float4 v = *(const float4*)(row + i4);
        float4 g = *(const float4*)(ln_g + i4);
        float4 be = *(const float4*)(ln_b + i4);
        ushort4 o;
        o.x = f2bf((v.x - mu) * rs * g.x + be.x);
        o.y = f2bf((v.y - mu) * rs * g.y + be.y);
        o.z = f2bf((v.z - mu) * rs * g.z + be.z);
        o.w = f2bf((v.w - mu) * rs * g.w + be.w);
        *(ushort4*)(xn + (size_t)b * D_TRF + i4) = o;
    }
}

// ---------------------------------------------------------------------------
// K3: QKV via MFMA, register-resident B-frags loaded straight from global
// ([f][e] layout IS the B-frag layout). No LDS. grid (256, 6):
// y = mat*2 + cf-half; each block: 64 rows x 80 cols of one matrix.
// ---------------------------------------------------------------------------
__global__ __launch_bounds__(256) void k_qkv3(const unsigned short* __restrict__ xn,
                                              const unsigned short* __restrict__ wqb,
                                              const unsigned short* __restrict__ wkb,
                                              const unsigned short* __restrict__ wvb,
                                              const float* __restrict__ bq,
                                              const float* __restrict__ bk,
                                              const float* __restrict__ bv,
                                              unsigned short* __restrict__ Qb,
                                              unsigned short* __restrict__ Kb,
                                              unsigned short* __restrict__ Vb) {
    int tid = threadIdx.x, wid = tid >> 6, lane = tid & 63;
    int l16 = lane & 15, quad = lane >> 4;
    int m0 = blockIdx.x * 64 + wid * 16;
    int sel = blockIdx.y;                 // 0..5
    int mat = sel >> 1;
    int cf0 = (sel & 1) * 5;

    const unsigned short* wsrc = (mat == 0) ? wqb : (mat == 1) ? wkb : wvb;
    const float* bias          = (mat == 0) ? bq  : (mat == 1) ? bk  : bv;
    unsigned short* outp       = (mat == 0) ? Qb  : (mat == 1) ? Kb  : Vb;

    short8 a[5];
    const unsigned short* arow = xn + (size_t)(m0 + l16) * E_ + quad * 8;
    #pragma unroll
    for (int kc = 0; kc < 5; ++kc) a[kc] = *(const short8*)(arow + kc * 32);

    #pragma unroll
    for (int c = 0; c < 5; ++c) {
        int cf = cf0 + c;
        floatx4 acc = {0.f, 0.f, 0.f, 0.f};
        const unsigned short* bp = wsrc + (size_t)(cf * 16 + l16) * E_ + quad * 8;
        #pragma unroll
        for (int kc = 0; kc < 5; ++kc) {
            short8 bf = *(const short8*)(bp + kc * 32);
            acc = __builtin_amdgcn_mfma_f32_16x16x32_bf16(a[kc], bf, acc, 0, 0, 0);
        }
        float bb = bias[cf * 16 + l16];
        size_t o = (size_t)(m0 + quad * 4) * E_ + cf * 16 + l16;
        #pragma unroll
        for (int r = 0; r < 4; ++r)
            outp[o + (size_t)r * E_] = f2bf(acc[r] + bb);
    }
}

// ---------------------------------------------------------------------------
// K4: attention per b (bf16 QKV): dot=Q K^T/sqrt(E); softmax over dim p;
//     h = att@V + cl (f32); also x2b = bf16(h*bt_gain + bt_bias)
// ---------------------------------------------------------------------------
__global__ __launch_bounds__(256) void k_attn(const unsigned short* __restrict__ Q,
                                              const unsigned short* __restrict__ K,
                                              const unsigned short* __restrict__ V,
                                              const float* __restrict__ cl,
                                              const float* __restrict__ bt_gain,
                                              const float* __restrict__ bt_bias,
                                              float* __restrict__ h,
                                              unsigned short* __restrict__ x2b) {
    int b = blockIdx.x, tid = threadIdx.x;
    __shared__ float Qs[P_ * E_];
    __shared__ float KsT[E_ * 33];
    __shared__ float att[P_ * P_];

    const unsigned short* Qg = Q + (size_t)b * D_TRF;
    const unsigned short* Kg = K + (size_t)b * D_TRF;
    for (int idx = tid; idx < D_TRF; idx += 256) {
        Qs[idx] = bf2f(Qg[idx]);
        int q = idx / E_, e = idx - q * E_;
        KsT[e * 33 + q] = bf2f(Kg[idx]);
    }
    __syncthreads();

    for (int idx = tid; idx < P_ * P_; idx += 256) {
        int p = idx >> 5, q = idx & 31;
        const float* qrow = Qs + p * E_;
        float a = 0.f;
        #pragma unroll 8
        for (int e = 0; e < E_; ++e) a += qrow[e] * KsT[e * 33 + q];
        att[idx] = a * INV_SCALE;
    }
    __syncthreads();

    if (tid < 32) {
        int q = tid;
        float mx = -1e30f;
        #pragma unroll
        for (int p = 0; p < P_; ++p) mx = fmaxf(mx, att[p * 32 + q]);
        float sum = 0.f;
        #pragma unroll
        for (int p = 0; p < P_; ++p) {
            float e_ = expf(att[p * 32 + q] - mx);
            att[p * 32 + q] = e_;
            sum += e_;
        }
        float inv = 1.f / sum;
        #pragma unroll
        for (int p = 0; p < P_; ++p) att[p * 32 + q] *= inv;
    }
    __syncthreads();

    float gg = bt_gain[0], bb2 = bt_bias[0];
    const unsigned short* Vg = V + (size_t)b * D_TRF;
    const float* clr = cl + (size_t)b * D_TRF;
    for (int idx = tid; idx < D_TRF; idx += 256) {
        int p = idx / E_, e = idx - p * E_;
        const float* ar = att + p * 32;
        float a = 0.f;
        #pragma unroll
        for (int q = 0; q < P_; ++q) a += ar[q] * bf2f(Vg[q * E_ + e]);
        float hv = a + clr[idx];
        h[(size_t)b * D_TRF + idx] = hv;
        x2b[(size_t)b * D_TRF + idx] = f2bf(hv * gg + bb2);
    }
}

// ---------------------------------------------------------------------------
// K5: Better_Transformer via MFMA, register B-frags from global (no LDS).
// grid (256, 2): y = cf-half. o = x2 @ wtb + bt_b; Supact; +h -> yb
// ---------------------------------------------------------------------------
__global__ __launch_bounds__(256) void k_bt3(const unsigned short* __restrict__ x2b,
                                             const unsigned short* __restrict__ wtb,
                                             const float* __restrict__ bt_b,
                                             const float* __restrict__ sup_g,
                                             const float* __restrict__ sup_b,
                                             const float* __restrict__ h,
                                             unsigned short* __restrict__ yb) {
    int tid = threadIdx.x, wid = tid >> 6, lane = tid & 63;
    int l16 = lane & 15, quad = lane >> 4;
    int m0 = blockIdx.x * 64 + wid * 16;
    int cf0 = blockIdx.y * 5;

    short8 a[5];
    const unsigned short* arow = x2b + (size_t)(m0 + l16) * E_ + quad * 8;
    #pragma unroll
    for (int kc = 0; kc < 5; ++kc) a[kc] = *(const short8*)(arow + kc * 32);

    #pragma unroll
    for (int c = 0; c < 5; ++c) {
        int cf = cf0 + c;
        floatx4 acc = {0.f, 0.f, 0.f, 0.f};
        const unsigned short* bp = wtb + (size_t)(cf * 16 + l16) * E_ + quad * 8;
        #pragma unroll
        for (int kc = 0; kc < 5; ++kc) {
            short8 bf = *(const short8*)(bp + kc * 32);
            acc = __builtin_amdgcn_mfma_f32_16x16x32_bf16(a[kc], bf, acc, 0, 0, 0);
        }
        int col = cf * 16 + l16;
        float bb = bt_b[col];
        #pragma unroll
        for (int r = 0; r < 4; ++r) {
            int row = m0 + quad * 4 + r;
            int p = row & 31;
            int i = p * E_ + col;
            float o = acc[r] + bb;
            float sig = 1.f / (1.f + expf(-sup_b[i] * o));
            float y = (sup_g[i] + sig * (1.f - sup_g[i])) * o + h[(size_t)row * E_ + col];
            yb[(size_t)row * E_ + col] = f2bf(y);
        }
    }
}

// ---------------------------------------------------------------------------
// K6: init out with bias terms: out[row,col] = lin_b[col]*g + ob
// ---------------------------------------------------------------------------
__global__ __launch_bounds__(256) void k_init_out(const float* __restrict__ lin_b,
                                                  const float* __restrict__ out_gain,
                                                  const float* __restrict__ out_bias,
                                                  float* __restrict__ out) {
    int col = blockIdx.x * 256 + threadIdx.x;
    if (col >= D_OUT) return;
    out[(size_t)blockIdx.y * D_OUT + col] = lin_b[col] * out_gain[0] + out_bias[0];
}

// ---------------------------------------------------------------------------
// K7: head GEMM, staged. Tile 128(m) x 96(n), BK=32, split-K=2.
// grid 256 = 32 n x 4 m x 2 sp. 4 waves 2x2, wave tile 64x48 (4x3 frags).
// atomicAdd epilogue onto bias-initialized out.
// ---------------------------------------------------------------------------
__global__ __launch_bounds__(256) void k_lin2(const unsigned short* __restrict__ yb,
                                              const unsigned short* __restrict__ wb,
                                              const float* __restrict__ out_gain,
                                              float* __restrict__ out) {
    __shared__ __align__(16) unsigned short As[128 * 32];
    __shared__ __align__(16) unsigned short Bs[96 * 32];
    int blk = blockIdx.x;
    int n = blk & 31, mt = (blk >> 5) & 3, sp = blk >> 7;
    int tid = threadIdx.x, wid = tid >> 6, lane = tid & 63;
    int wm = wid >> 1, wn = wid & 1;
    int l16 = lane & 15, quad = lane >> 4;
    int m_base = mt * 128;

    const unsigned short* Abase = yb + (size_t)m_base * D_TRF;
    const unsigned short* Bbase = wb + (size_t)(n * 96) * D_TRF;

    int uA0 = tid, uA1 = tid + 256;
    int uB0 = tid, uB1 = tid + 128;          // uB1 used by waves 2,3 only

    floatx4 acc[4][3];
    #pragma unroll
    for (int i = 0; i < 4; ++i)
        #pragma unroll
        for (int j = 0; j < 3; ++j) acc[i][j] = (floatx4){0.f, 0.f, 0.f, 0.f};

    int k0 = sp * (D_TRF / 2);
    for (int kk = 0; kk < D_TRF / 2; kk += 32) {
        int k = k0 + kk;
        load_lds16(Abase + (size_t)(uA0 >> 2) * D_TRF + k + (uA0 & 3) * 8, &As[uA0 * 8]);
        load_lds16(Abase + (size_t)(uA1 >> 2) * D_TRF + k + (uA1 & 3) * 8, &As[uA1 * 8]);
        load_lds16(Bbase + (size_t)(uB0 >> 2) * D_TRF + k + (uB0 & 3) * 8, &Bs[uB0 * 8]);
        if (wid >= 2)
            load_lds16(Bbase + (size_t)(uB1 >> 2) * D_TRF + k + (uB1 & 3) * 8, &Bs[uB1 * 8]);
        __syncthreads();

        short8 af[4], bf[3];
        #pragma unroll
        for (int fi = 0; fi < 4; ++fi)
            af[fi] = *(const short8*)(&As[(wm * 64 + fi * 16 + l16) * 32 + quad * 8]);
        #pragma unroll
        for (int fj = 0; fj < 3; ++fj)
            bf[fj] = *(const short8*)(&Bs[(wn * 48 + fj * 16 + l16) * 32 + quad * 8]);
        #pragma unroll
        for (int fi = 0; fi < 4; ++fi)
            #pragma unroll
            for (int fj = 0; fj < 3; ++fj)
                acc[fi][fj] = __builtin_amdgcn_mfma_f32_16x16x32_bf16(af[fi], bf[fj], acc[fi][fj], 0, 0, 0);
        __syncthreads();
    }

    float g = out_gain[0];
    #pragma unroll
    for (int fi = 0; fi < 4; ++fi) {
        int row = m_base + wm * 64 + fi * 16 + quad * 4;
        #pragma unroll
        for (int fj = 0; fj < 3; ++fj) {
            int col = n * 96 + wn * 48 + fj * 16 + l16;
            if (col >= D_OUT) continue;
            #pragma unroll
            for (int r = 0; r < 4; ++r)
                atomicAdd(&out[(size_t)(row + r) * D_OUT + col], acc[fi][fj][r] * g);
        }
    }
}

// ---------------------------------------------------------------------------
// Workspace layout (bytes)
// ---------------------------------------------------------------------------
#define SZ_ROWF ((size_t)B_ * D_TRF * 4)           // 10,485,760
#define SZ_ROWB ((size_t)B_ * D_TRF * 2)           // 5,242,880
#define OFF_CL  ((size_t)0)
#define OFF_H   (OFF_CL + SZ_ROWF)
#define OFF_XN  (OFF_H + SZ_ROWF)                  // xn bf16; reused as x2b
#define OFF_QB  (OFF_XN + SZ_ROWB)
#define OFF_KB  (OFF_QB + SZ_ROWB)
#define OFF_VB  (OFF_KB + SZ_ROWB)
#define OFF_YB  (OFF_VB + SZ_ROWB)
#define OFF_WSM (OFF_YB + SZ_ROWB)                 // 4 x 51200 B
#define OFF_WB  (OFF_WSM + (size_t)4 * E_ * E_ * 2)
// end = OFF_WB + 3072*5120*2 = 78,848,000 bytes

extern "C" void kernel_launch(void* const* d_in, const int* in_sizes, int n_in,
                              void* d_out, int out_size, void* d_ws, size_t ws_size,
                              hipStream_t stream) {
    const float* x        = (const float*)d_in[0];
    const float* stdv     = (const float*)d_in[1];
    const float* meanv    = (const float*)d_in[2];
    const float* mat      = (const float*)d_in[3];
    const float* ln_g     = (const float*)d_in[4];
    const float* ln_b     = (const float*)d_in[5];
    const float* wq       = (const float*)d_in[6];
    const float* bq       = (const float*)d_in[7];
    const float* wk       = (const float*)d_in[8];
    const float* bk       = (const float*)d_in[9];
    const float* wv       = (const float*)d_in[10];
    const float* bv       = (const float*)d_in[11];
    const float* bt_w     = (const float*)d_in[12];
    const float* bt_b     = (const float*)d_in[13];
    const float* bt_gain  = (const float*)d_in[14];
    const float* bt_bias  = (const float*)d_in[15];
    const float* sup_g    = (const float*)d_in[16];
    const float* sup_b    = (const float*)d_in[17];
    const float* lin_w    = (const float*)d_in[18];
    const float* lin_b    = (const float*)d_in[19];
    const float* out_gain = (const float*)d_in[20];
    const float* out_bias = (const float*)d_in[21];

    char* ws = (char*)d_ws;
    float* cl = (float*)(ws + OFF_CL);
    float* h  = (float*)(ws + OFF_H);
    unsigned short* xn  = (unsigned short*)(ws + OFF_XN);
    unsigned short* x2b = xn;   // xn dead after k_qkv3
    unsigned short* Qb  = (unsigned short*)(ws + OFF_QB);
    unsigned short* Kb  = (unsigned short*)(ws + OFF_KB);
    unsigned short* Vb  = (unsigned short*)(ws + OFF_VB);
    unsigned short* yb  = (unsigned short*)(ws + OFF_YB);
    unsigned short* wqb = (unsigned short*)(ws + OFF_WSM);
    unsigned short* wkb = wqb + E_ * E_;
    unsigned short* wvb = wkb + E_ * E_;
    unsigned short* wtb = wvb + E_ * E_;
    unsigned short* wb  = (unsigned short*)(ws + OFF_WB);
    float* out = (float*)d_out;

    k_castw<<<15360, 256, 0, stream>>>(lin_w, wb);
    k_cast_small<<<100, 256, 0, stream>>>(wq, wk, wv, bt_w, wqb, wkb, wvb, wtb);
    k_cl<<<dim3(64, 4), 256, 0, stream>>>(x, stdv, meanv, mat, cl);
    k_ln<<<512, 256, 0, stream>>>(cl, ln_g, ln_b, xn);
    k_qkv3<<<dim3(256, 6), 256, 0, stream>>>(xn, wqb, wkb, wvb, bq, bk, bv, Qb, Kb, Vb);
    k_attn<<<512, 256, 0, stream>>>(Qb, Kb, Vb, cl, bt_gain, bt_bias, h, x2b);
    k_bt3<<<dim3(256, 2), 256, 0, stream>>>(x2b, wtb, bt_b, sup_g, sup_b, h, yb);
    k_init_out<<<dim3(12, B_), 256, 0, stream>>>(lin_b, out_gain, out_bias, out);
    k_lin2<<<256, 256, 0, stream>>>(yb, wb, out_gain, out);
}

// Round 6
// 307.617 us; speedup vs baseline: 1.6073x; 1.1156x over previous
//
#include <hip/hip_runtime.h>

// Problem constants
#define B_    512
#define D_TRF 5120
#define P_    32
#define E_    160
#define D_OUT 3000
#define PAD_  61
#define D_CL  4998
#define INV_SCALE 0.07905694150420949f   // 1/sqrt(160)
#define N_PAD 3072          // lin_w rows padded (32 tiles of 96)

typedef __attribute__((ext_vector_type(4))) float floatx4;
typedef __attribute__((ext_vector_type(16))) float floatx16;
typedef __attribute__((ext_vector_type(8))) short short8;

static __device__ __forceinline__ unsigned short f2bf(float f) {
    unsigned int u = __float_as_uint(f);
    unsigned int r = (u + 0x7fffu + ((u >> 16) & 1u)) >> 16;
    return (unsigned short)r;
}
static __device__ __forceinline__ float bf2f(unsigned short u) {
    return __uint_as_float(((unsigned int)u) << 16);
}
static __device__ __forceinline__ void load_lds16(const void* g, void* lds) {
    __builtin_amdgcn_global_load_lds(
        (const __attribute__((address_space(1))) unsigned int*)g,
        (__attribute__((address_space(3))) unsigned int*)lds, 16, 0, 0);
}

// ---------------------------------------------------------------------------
// K0: cast lin_w [3000,5120] f32 -> [3072,5120] bf16 (pad rows zeroed)
// ---------------------------------------------------------------------------
__global__ __launch_bounds__(256) void k_castw(const float* __restrict__ w,
                                               unsigned short* __restrict__ wb) {
    size_t i4 = ((size_t)blockIdx.x * 256 + threadIdx.x) * 4;
    size_t o = i4 / D_TRF;
    ushort4 s;
    if (o < D_OUT) {
        float4 v = *(const float4*)(w + i4);
        s.x = f2bf(v.x); s.y = f2bf(v.y); s.z = f2bf(v.z); s.w = f2bf(v.w);
    } else {
        s.x = s.y = s.z = s.w = 0;
    }
    *(ushort4*)(wb + i4) = s;
}

// ---------------------------------------------------------------------------
// K0b: cast wq/wk/wv ([f][e], already B-operand layout) to bf16;
//      transpose bt_w -> wtb[f][e] = bt_w[e][f].
// ---------------------------------------------------------------------------
__global__ __launch_bounds__(256) void k_cast_small(const float* __restrict__ wq,
                                                    const float* __restrict__ wk,
                                                    const float* __restrict__ wv,
                                                    const float* __restrict__ btw,
                                                    unsigned short* __restrict__ wqb,
                                                    unsigned short* __restrict__ wkb,
                                                    unsigned short* __restrict__ wvb,
                                                    unsigned short* __restrict__ wtb) {
    int idx = blockIdx.x * 256 + threadIdx.x;   // < 25600
    wqb[idx] = f2bf(wq[idx]);
    wkb[idx] = f2bf(wk[idx]);
    wvb[idx] = f2bf(wv[idx]);
    int f = idx / E_, e = idx - f * E_;
    wtb[idx] = f2bf(btw[(size_t)e * E_ + f]);
}

// ---------------------------------------------------------------------------
// K1: cl = (x*std+mean) @ mat, with 61-zero pad both sides -> [512,5120]
// ---------------------------------------------------------------------------
__global__ __launch_bounds__(256) void k_cl(const float* __restrict__ x,
                                            const float* __restrict__ stdv,
                                            const float* __restrict__ meanv,
                                            const float* __restrict__ mat,
                                            float* __restrict__ cl) {
    int bg = blockIdx.x, jc = blockIdx.y, tid = threadIdx.x;
    __shared__ float t[8 * 64];
    for (int idx = tid; idx < 8 * 64; idx += 256) {
        int i = idx >> 6, k = idx & 63;
        t[idx] = x[(size_t)(bg * 8 + i) * 64 + k] * stdv[k] + meanv[k];
    }
    __syncthreads();

    if (jc == 0) {
        for (int idx = tid; idx < 8 * PAD_; idx += 256) {
            int i = idx / PAD_, jj = idx - i * PAD_;
            cl[(size_t)(bg * 8 + i) * D_TRF + jj] = 0.f;
        }
    } else if (jc == 3) {
        for (int idx = tid; idx < 8 * PAD_; idx += 256) {
            int i = idx / PAD_, jj = idx - i * PAD_;
            cl[(size_t)(bg * 8 + i) * D_TRF + (D_TRF - PAD_) + jj] = 0.f;
        }
    }

    int j0 = jc * 1250;
    int jend = min(D_CL, j0 + 1250);
    for (int j = j0 + tid; j < jend; j += 256) {
        float acc[8] = {};
        #pragma unroll 16
        for (int k = 0; k < 64; ++k) {
            float m = mat[(size_t)k * D_CL + j];
            #pragma unroll
            for (int i = 0; i < 8; ++i) acc[i] += t[i * 64 + k] * m;
        }
        #pragma unroll
        for (int i = 0; i < 8; ++i)
            cl[(size_t)(bg * 8 + i) * D_TRF + PAD_ + j] = acc[i];
    }
}

// ---------------------------------------------------------------------------
// K2: LayerNorm cl row -> xn bf16 [16384,160]. grid = 512 (one b each)
// ---------------------------------------------------------------------------
__global__ __launch_bounds__(256) void k_ln(const float* __restrict__ cl,
                                            const float* __restrict__ ln_g,
                                            const float* __restrict__ ln_b,
                                            unsigned short* __restrict__ xn) {
    int b = blockIdx.x, tid = threadIdx.x;
    __shared__ float redA[4], redB[4];
    __shared__ float sMu, sRstd;
    const float* row = cl + (size_t)b * D_TRF;

    float s = 0.f, s2 = 0.f;
    #pragma unroll
    for (int it = 0; it < 5; ++it) {
        int i4 = (it * 256 + tid) * 4;
        float4 v = *(const float4*)(row + i4);
        s += v.x + v.y + v.z + v.w;
        s2 += v.x * v.x + v.y * v.y + v.z * v.z + v.w * v.w;
    }
    #pragma unroll
    for (int off = 32; off; off >>= 1) {
        s  += __shfl_down(s, off);
        s2 += __shfl_down(s2, off);
    }
    if ((tid & 63) == 0) { redA[tid >> 6] = s; redB[tid >> 6] = s2; }
    __syncthreads();
    if (tid == 0) {
        float S = redA[0] + redA[1] + redA[2] + redA[3];
        float S2 = redB[0] + redB[1] + redB[2] + redB[3];
        float mu = S / (float)D_TRF;
        float var = S2 / (float)D_TRF - mu * mu;
        sMu = mu; sRstd = rsqrtf(var + 1e-5f);
    }
    __syncthreads();
    float mu = sMu, rs = sRstd;
    #pragma unroll
    for (int it = 0; it < 5; ++it) {
        int i4 = (it * 256 + tid) * 4;
        float4 v = *(const float4*)(row + i4);
        float4 g = *(const float4*)(ln_g + i4);
        float4 be = *(const float4*)(ln_b + i4);
        ushort4 o;
        o.x = f2bf((v.x - mu) * rs * g.x + be.x);
        o.y = f2bf((v.y - mu) * rs * g.y + be.y);
        o.z = f2bf((v.z - mu) * rs * g.z + be.z);
        o.w = f2bf((v.w - mu) * rs * g.w + be.w);
        *(ushort4*)(xn + (size_t)b * D_TRF + i4) = o;
    }
}

// ---------------------------------------------------------------------------
// K3: QKV via MFMA, register-resident B-frags loaded straight from global
// ---------------------------------------------------------------------------
__global__ __launch_bounds__(256) void k_qkv3(const unsigned short* __restrict__ xn,
                                              const unsigned short* __restrict__ wqb,
                                              const unsigned short* __restrict__ wkb,
                                              const unsigned short* __restrict__ wvb,
                                              const float* __restrict__ bq,
                                              const float* __restrict__ bk,
                                              const float* __restrict__ bv,
                                              unsigned short* __restrict__ Qb,
                                              unsigned short* __restrict__ Kb,
                                              unsigned short* __restrict__ Vb) {
    int tid = threadIdx.x, wid = tid >> 6, lane = tid & 63;
    int l16 = lane & 15, quad = lane >> 4;
    int m0 = blockIdx.x * 64 + wid * 16;
    int sel = blockIdx.y;                 // 0..5
    int mat = sel >> 1;
    int cf0 = (sel & 1) * 5;

    const unsigned short* wsrc = (mat == 0) ? wqb : (mat == 1) ? wkb : wvb;
    const float* bias          = (mat == 0) ? bq  : (mat == 1) ? bk  : bv;
    unsigned short* outp       = (mat == 0) ? Qb  : (mat == 1) ? Kb  : Vb;

    short8 a[5];
    const unsigned short* arow = xn + (size_t)(m0 + l16) * E_ + quad * 8;
    #pragma unroll
    for (int kc = 0; kc < 5; ++kc) a[kc] = *(const short8*)(arow + kc * 32);

    #pragma unroll
    for (int c = 0; c < 5; ++c) {
        int cf = cf0 + c;
        floatx4 acc = {0.f, 0.f, 0.f, 0.f};
        const unsigned short* bp = wsrc + (size_t)(cf * 16 + l16) * E_ + quad * 8;
        #pragma unroll
        for (int kc = 0; kc < 5; ++kc) {
            short8 bf = *(const short8*)(bp + kc * 32);
            acc = __builtin_amdgcn_mfma_f32_16x16x32_bf16(a[kc], bf, acc, 0, 0, 0);
        }
        float bb = bias[cf * 16 + l16];
        size_t o = (size_t)(m0 + quad * 4) * E_ + cf * 16 + l16;
        #pragma unroll
        for (int r = 0; r < 4; ++r)
            outp[o + (size_t)r * E_] = f2bf(acc[r] + bb);
    }
}

// ---------------------------------------------------------------------------
// K4: MFMA attention, one wave per b. grid 512 x 64 threads.
// S = QK^T via 32x32x16 (A/B frags direct from global: m=lane%32,
// k=(lane/32)*8+j contiguous 16B). Softmax over p = C-layout rows:
// in-lane 16 regs + shfl_xor(32). att->LDS (32x40 bf16) -> A-frags via
// ds_read_b128. PV B-frags = 8x scalar b16 global loads (each V elem once).
// Epilogue: h = PV + cl (f32) and x2b = bf16(h*gain+bias), C-layout writes.
// ---------------------------------------------------------------------------
__global__ __launch_bounds__(64) void k_attn2(const unsigned short* __restrict__ Q,
                                              const unsigned short* __restrict__ K,
                                              const unsigned short* __restrict__ V,
                                              const float* __restrict__ cl,
                                              const float* __restrict__ bt_gain,
                                              const float* __restrict__ bt_bias,
                                              float* __restrict__ h,
                                              unsigned short* __restrict__ x2b) {
    int b = blockIdx.x;
    int lane = threadIdx.x;
    int l32 = lane & 31, hi = lane >> 5;
    __shared__ __align__(16) unsigned short Satt[32 * 40];   // row stride 40 bf16

    const unsigned short* Qg = Q + (size_t)b * D_TRF;
    const unsigned short* Kg = K + (size_t)b * D_TRF;
    const unsigned short* Vg = V + (size_t)b * D_TRF;

    // ---- S = Q K^T ----
    floatx16 S = {0.f, 0.f, 0.f, 0.f, 0.f, 0.f, 0.f, 0.f,
                  0.f, 0.f, 0.f, 0.f, 0.f, 0.f, 0.f, 0.f};
    #pragma unroll
    for (int kc = 0; kc < 10; ++kc) {
        int e0 = kc * 16;
        short8 aq = *(const short8*)(Qg + l32 * E_ + e0 + hi * 8);
        short8 bk = *(const short8*)(Kg + l32 * E_ + e0 + hi * 8);
        S = __builtin_amdgcn_mfma_f32_32x32x16_bf16(aq, bk, S, 0, 0, 0);
    }

    // ---- softmax over p (rows); col q = l32 fixed per lane pair ----
    float mx = -1e30f;
    #pragma unroll
    for (int r = 0; r < 16; ++r) { S[r] *= INV_SCALE; mx = fmaxf(mx, S[r]); }
    mx = fmaxf(mx, __shfl_xor(mx, 32));
    float ex[16];
    float sum = 0.f;
    #pragma unroll
    for (int r = 0; r < 16; ++r) { ex[r] = expf(S[r] - mx); sum += ex[r]; }
    sum += __shfl_xor(sum, 32);
    float inv = 1.f / sum;

    // ---- att -> LDS in [p][q] layout (bf16) ----
    #pragma unroll
    for (int r = 0; r < 16; ++r) {
        int p = (r & 3) + 8 * (r >> 2) + 4 * hi;
        Satt[p * 40 + l32] = f2bf(ex[r] * inv);
    }
    __syncthreads();

    // ---- A-frags for PV: att[m=l32][k=hi*8+j (+16)] ----
    short8 a0 = *(const short8*)(&Satt[l32 * 40 + hi * 8]);
    short8 a1 = *(const short8*)(&Satt[l32 * 40 + 16 + hi * 8]);

    const float* clr = cl + (size_t)b * D_TRF;
    float gg = bt_gain[0], bb2 = bt_bias[0];

    #pragma unroll
    for (int t = 0; t < 5; ++t) {
        int e0 = t * 32;
        short8 b0, b1;
        #pragma unroll
        for (int j = 0; j < 8; ++j) {
            b0[j] = (short)Vg[(size_t)(hi * 8 + j) * E_ + e0 + l32];
            b1[j] = (short)Vg[(size_t)(16 + hi * 8 + j) * E_ + e0 + l32];
        }
        floatx16 acc = {0.f, 0.f, 0.f, 0.f, 0.f, 0.f, 0.f, 0.f,
                        0.f, 0.f, 0.f, 0.f, 0.f, 0.f, 0.f, 0.f};
        acc = __builtin_amdgcn_mfma_f32_32x32x16_bf16(a0, b0, acc, 0, 0, 0);
        acc = __builtin_amdgcn_mfma_f32_32x32x16_bf16(a1, b1, acc, 0, 0, 0);
        #pragma unroll
        for (int r = 0; r < 16; ++r) {
            int p = (r & 3) + 8 * (r >> 2) + 4 * hi;
            int idx = p * E_ + e0 + l32;
            float hv = acc[r] + clr[idx];
            h[(size_t)b * D_TRF + idx] = hv;
            x2b[(size_t)b * D_TRF + idx] = f2bf(hv * gg + bb2);
        }
    }
}

// ---------------------------------------------------------------------------
// K5: Better_Transformer via MFMA, register B-frags from global (no LDS).
// ---------------------------------------------------------------------------
__global__ __launch_bounds__(256) void k_bt3(const unsigned short* __restrict__ x2b,
                                             const unsigned short* __restrict__ wtb,
                                             const float* __restrict__ bt_b,
                                             const float* __restrict__ sup_g,
                                             const float* __restrict__ sup_b,
                                             const float* __restrict__ h,
                                             unsigned short* __restrict__ yb) {
    int tid = threadIdx.x, wid = tid >> 6, lane = tid & 63;
    int l16 = lane & 15, quad = lane >> 4;
    int m0 = blockIdx.x * 64 + wid * 16;
    int cf0 = blockIdx.y * 5;

    short8 a[5];
    const unsigned short* arow = x2b + (size_t)(m0 + l16) * E_ + quad * 8;
    #pragma unroll
    for (int kc = 0; kc < 5; ++kc) a[kc] = *(const short8*)(arow + kc * 32);

    #pragma unroll
    for (int c = 0; c < 5; ++c) {
        int cf = cf0 + c;
        floatx4 acc = {0.f, 0.f, 0.f, 0.f};
        const unsigned short* bp = wtb + (size_t)(cf * 16 + l16) * E_ + quad * 8;
        #pragma unroll
        for (int kc = 0; kc < 5; ++kc) {
            short8 bf = *(const short8*)(bp + kc * 32);
            acc = __builtin_amdgcn_mfma_f32_16x16x32_bf16(a[kc], bf, acc, 0, 0, 0);
        }
        int col = cf * 16 + l16;
        float bb = bt_b[col];
        #pragma unroll
        for (int r = 0; r < 4; ++r) {
            int row = m0 + quad * 4 + r;
            int p = row & 31;
            int i = p * E_ + col;
            float o = acc[r] + bb;
            float sig = 1.f / (1.f + expf(-sup_b[i] * o));
            float y = (sup_g[i] + sig * (1.f - sup_g[i])) * o + h[(size_t)row * E_ + col];
            yb[(size_t)row * E_ + col] = f2bf(y);
        }
    }
}

// ---------------------------------------------------------------------------
// K6: init out with bias terms: out[row,col] = lin_b[col]*g + ob
// ---------------------------------------------------------------------------
__global__ __launch_bounds__(256) void k_init_out(const float* __restrict__ lin_b,
                                                  const float* __restrict__ out_gain,
                                                  const float* __restrict__ out_bias,
                                                  float* __restrict__ out) {
    int col = blockIdx.x * 256 + threadIdx.x;
    if (col >= D_OUT) return;
    out[(size_t)blockIdx.y * D_OUT + col] = lin_b[col] * out_gain[0] + out_bias[0];
}

// ---------------------------------------------------------------------------
// K7: head GEMM, staged. Tile 128(m) x 96(n), BK=32, split-K=2.
// ---------------------------------------------------------------------------
__global__ __launch_bounds__(256) void k_lin2(const unsigned short* __restrict__ yb,
                                              const unsigned short* __restrict__ wb,
                                              const float* __restrict__ out_gain,
                                              float* __restrict__ out) {
    __shared__ __align__(16) unsigned short As[128 * 32];
    __shared__ __align__(16) unsigned short Bs[96 * 32];
    int blk = blockIdx.x;
    int n = blk & 31, mt = (blk >> 5) & 3, sp = blk >> 7;
    int tid = threadIdx.x, wid = tid >> 6, lane = tid & 63;
    int wm = wid >> 1, wn = wid & 1;
    int l16 = lane & 15, quad = lane >> 4;
    int m_base = mt * 128;

    const unsigned short* Abase = yb + (size_t)m_base * D_TRF;
    const unsigned short* Bbase = wb + (size_t)(n * 96) * D_TRF;

    int uA0 = tid, uA1 = tid + 256;
    int uB0 = tid, uB1 = tid + 128;          // uB1 used by waves 2,3 only

    floatx4 acc[4][3];
    #pragma unroll
    for (int i = 0; i < 4; ++i)
        #pragma unroll
        for (int j = 0; j < 3; ++j) acc[i][j] = (floatx4){0.f, 0.f, 0.f, 0.f};

    int k0 = sp * (D_TRF / 2);
    for (int kk = 0; kk < D_TRF / 2; kk += 32) {
        int k = k0 + kk;
        load_lds16(Abase + (size_t)(uA0 >> 2) * D_TRF + k + (uA0 & 3) * 8, &As[uA0 * 8]);
        load_lds16(Abase + (size_t)(uA1 >> 2) * D_TRF + k + (uA1 & 3) * 8, &As[uA1 * 8]);
        load_lds16(Bbase + (size_t)(uB0 >> 2) * D_TRF + k + (uB0 & 3) * 8, &Bs[uB0 * 8]);
        if (wid >= 2)
            load_lds16(Bbase + (size_t)(uB1 >> 2) * D_TRF + k + (uB1 & 3) * 8, &Bs[uB1 * 8]);
        __syncthreads();

        short8 af[4], bf[3];
        #pragma unroll
        for (int fi = 0; fi < 4; ++fi)
            af[fi] = *(const short8*)(&As[(wm * 64 + fi * 16 + l16) * 32 + quad * 8]);
        #pragma unroll
        for (int fj = 0; fj < 3; ++fj)
            bf[fj] = *(const short8*)(&Bs[(wn * 48 + fj * 16 + l16) * 32 + quad * 8]);
        #pragma unroll
        for (int fi = 0; fi < 4; ++fi)
            #pragma unroll
            for (int fj = 0; fj < 3; ++fj)
                acc[fi][fj] = __builtin_amdgcn_mfma_f32_16x16x32_bf16(af[fi], bf[fj], acc[fi][fj], 0, 0, 0);
        __syncthreads();
    }

    float g = out_gain[0];
    #pragma unroll
    for (int fi = 0; fi < 4; ++fi) {
        int row = m_base + wm * 64 + fi * 16 + quad * 4;
        #pragma unroll
        for (int fj = 0; fj < 3; ++fj) {
            int col = n * 96 + wn * 48 + fj * 16 + l16;
            if (col >= D_OUT) continue;
            #pragma unroll
            for (int r = 0; r < 4; ++r)
                atomicAdd(&out[(size_t)(row + r) * D_OUT + col], acc[fi][fj][r] * g);
        }
    }
}

// ---------------------------------------------------------------------------
// Workspace layout (bytes)
// ---------------------------------------------------------------------------
#define SZ_ROWF ((size_t)B_ * D_TRF * 4)           // 10,485,760
#define SZ_ROWB ((size_t)B_ * D_TRF * 2)           // 5,242,880
#define OFF_CL  ((size_t)0)
#define OFF_H   (OFF_CL + SZ_ROWF)
#define OFF_XN  (OFF_H + SZ_ROWF)                  // xn bf16; reused as x2b
#define OFF_QB  (OFF_XN + SZ_ROWB)
#define OFF_KB  (OFF_QB + SZ_ROWB)
#define OFF_VB  (OFF_KB + SZ_ROWB)
#define OFF_YB  (OFF_VB + SZ_ROWB)
#define OFF_WSM (OFF_YB + SZ_ROWB)                 // 4 x 51200 B
#define OFF_WB  (OFF_WSM + (size_t)4 * E_ * E_ * 2)
// end = OFF_WB + 3072*5120*2 = 78,848,000 bytes

extern "C" void kernel_launch(void* const* d_in, const int* in_sizes, int n_in,
                              void* d_out, int out_size, void* d_ws, size_t ws_size,
                              hipStream_t stream) {
    const float* x        = (const float*)d_in[0];
    const float* stdv     = (const float*)d_in[1];
    const float* meanv    = (const float*)d_in[2];
    const float* mat      = (const float*)d_in[3];
    const float* ln_g     = (const float*)d_in[4];
    const float* ln_b     = (const float*)d_in[5];
    const float* wq       = (const float*)d_in[6];
    const float* bq       = (const float*)d_in[7];
    const float* wk       = (const float*)d_in[8];
    const float* bk       = (const float*)d_in[9];
    const float* wv       = (const float*)d_in[10];
    const float* bv       = (const float*)d_in[11];
    const float* bt_w     = (const float*)d_in[12];
    const float* bt_b     = (const float*)d_in[13];
    const float* bt_gain  = (const float*)d_in[14];
    const float* bt_bias  = (const float*)d_in[15];
    const float* sup_g    = (const float*)d_in[16];
    const float* sup_b    = (const float*)d_in[17];
    const float* lin_w    = (const float*)d_in[18];
    const float* lin_b    = (const float*)d_in[19];
    const float* out_gain = (const float*)d_in[20];
    const float* out_bias = (const float*)d_in[21];

    char* ws = (char*)d_ws;
    float* cl = (float*)(ws + OFF_CL);
    float* h  = (float*)(ws + OFF_H);
    unsigned short* xn  = (unsigned short*)(ws + OFF_XN);
    unsigned short* x2b = xn;   // xn dead after k_qkv3
    unsigned short* Qb  = (unsigned short*)(ws + OFF_QB);
    unsigned short* Kb  = (unsigned short*)(ws + OFF_KB);
    unsigned short* Vb  = (unsigned short*)(ws + OFF_VB);
    unsigned short* yb  = (unsigned short*)(ws + OFF_YB);
    unsigned short* wqb = (unsigned short*)(ws + OFF_WSM);
    unsigned short* wkb = wqb + E_ * E_;
    unsigned short* wvb = wkb + E_ * E_;
    unsigned short* wtb = wvb + E_ * E_;
    unsigned short* wb  = (unsigned short*)(ws + OFF_WB);
    float* out = (float*)d_out;

    k_castw<<<15360, 256, 0, stream>>>(lin_w, wb);
    k_cast_small<<<100, 256, 0, stream>>>(wq, wk, wv, bt_w, wqb, wkb, wvb, wtb);
    k_cl<<<dim3(64, 4), 256, 0, stream>>>(x, stdv, meanv, mat, cl);
    k_ln<<<512, 256, 0, stream>>>(cl, ln_g, ln_b, xn);
    k_qkv3<<<dim3(256, 6), 256, 0, stream>>>(xn, wqb, wkb, wvb, bq, bk, bv, Qb, Kb, Vb);
    k_attn2<<<512, 64, 0, stream>>>(Qb, Kb, Vb, cl, bt_gain, bt_bias, h, x2b);
    k_bt3<<<dim3(256, 2), 256, 0, stream>>>(x2b, wtb, bt_b, sup_g, sup_b, h, yb);
    k_init_out<<<dim3(12, B_), 256, 0, stream>>>(lin_b, out_gain, out_bias, out);
    k_lin2<<<256, 256, 0, stream>>>(yb, wb, out_gain, out);
}